// Round 4
// baseline (495.129 us; speedup 1.0000x reference)
//
#include <hip/hip_runtime.h>
#include <math.h>

// Problem constants
constexpr int Bn = 2, Ln = 128;

// log(expm1(0.01))
#define LR_SHIFT (-4.6001660040607144f)

// ---------------------------------------------------------------------------
// Workspace layout (floats)
// ---------------------------------------------------------------------------
constexpr int OFF_Q      = 0;        // [256 tok][256]
constexpr int OFF_K      = 65536;    // [256 tok][256]
constexpr int OFF_V      = 131072;   // [256 tok][256]
constexpr int OFF_X2     = 196608;   // [256 tok][256]
constexpr int OFF_SILD   = 262144;   // [256 tok][256] silu_backward(Z1)
constexpr int OFF_XQ     = 327680;   // [256 tok][256]
constexpr int OFF_KT     = 393216;   // [B][256 d][128 l]
constexpr int OFF_X2T    = 458752;   // [B][256 h][128 l]
constexpr int OFF_A      = 524288;   // [B][128 l][128 m]  A = Dm@M
constexpr int OFF_B1CAT  = 557056;   // [B][640][256]: rows 0-127 GZ1, 128-383 W1t, 384-639 mW1t
constexpr int OFF_B2CAT  = 884736;   // [B][640][256]: rows 0-127 GZ2, 128-383 W2t, 384-639 mW2t
constexpr int OFF_A1CAT  = 1212416;  // [B][128 l][640]: cols 0-127 P1, 128-383 wd*q, 384-639 -c*q
constexpr int OFF_A2CAT  = 1376256;  // [B][128 l][640]
constexpr int OFF_FC     = 1540096;  // [3][256] raw lr/mom/wd projections
constexpr int OFF_LR     = 1540864;  // [B][128]
constexpr int OFF_PM     = 1541120;  // [B][128]
constexpr int OFF_PD     = 1541376;  // [B][128]
constexpr int OFF_MOMCUM = 1541632;  // [B][128]
constexpr int OFF_WDCUM  = 1541888;  // [B][128]
constexpr int OFF_C      = 1542144;  // [B][128]
constexpr int OFF_BAR    = 1542656;  // 2 unsigned barrier words

// Output offsets (floats), tuple order
constexpr int OUT_ZQ2  = 0;
constexpr int OUT_W1P  = 65536;
constexpr int OUT_B1P  = 196608;
constexpr int OUT_W2P  = 197120;
constexpr int OUT_B2P  = 328192;
constexpr int OUT_MGW1 = 328704;
constexpr int OUT_MGB1 = 459776;
constexpr int OUT_MGW2 = 460288;
constexpr int OUT_MGB2 = 591360;

constexpr int NBLK = 256;

__device__ __forceinline__ float softplus_f(float z) {
    return fmaxf(z, 0.0f) + log1pf(expf(-fabsf(z)));
}

__device__ __forceinline__ float dot4(float4 a, float4 b) {
    return a.x * b.x + a.y * b.y + a.z * b.z + a.w * b.w;
}

// ---------------------------------------------------------------------------
// Grid barrier: sense-reversing, device(agent)-scope atomics. All NBLK blocks
// are co-resident (256 blocks x 4 waves x ~13KB LDS: capacity >= 2 blocks/CU).
// ---------------------------------------------------------------------------
__device__ __forceinline__ void grid_barrier(unsigned* bar) {
    __syncthreads();
    if (threadIdx.x == 0) {
        unsigned* cnt = bar;
        unsigned* gen = bar + 1;
        unsigned g = __hip_atomic_load(gen, __ATOMIC_ACQUIRE, __HIP_MEMORY_SCOPE_AGENT);
        unsigned arrived = __hip_atomic_fetch_add(cnt, 1u, __ATOMIC_ACQ_REL,
                                                  __HIP_MEMORY_SCOPE_AGENT);
        if (arrived == (unsigned)NBLK - 1) {
            __hip_atomic_store(cnt, 0u, __ATOMIC_RELAXED, __HIP_MEMORY_SCOPE_AGENT);
            __hip_atomic_fetch_add(gen, 1u, __ATOMIC_ACQ_REL, __HIP_MEMORY_SCOPE_AGENT);
        } else {
            while (__hip_atomic_load(gen, __ATOMIC_ACQUIRE,
                                     __HIP_MEMORY_SCOPE_AGENT) == g)
                __builtin_amdgcn_s_sleep(8);
        }
    }
    __syncthreads();
}

// ---------------------------------------------------------------------------
// GEMM tile: 32x64 output, 256 threads, 2x4 register tile, KC=32.
// A: [32 rows][K] (lda), B: [K][64 cols] (ldb). smem >= 3136 floats.
// ---------------------------------------------------------------------------
__device__ __forceinline__ void gemm_tile(
    const float* A, int lda, const float* B, int ldb, int K,
    float* smem, float4& c0, float4& c1) {
    float (*As)[34] = (float(*)[34])smem;            // [k][m]
    float (*Bs)[64] = (float(*)[64])(smem + 1088);   // [k][n]
    const int t = threadIdx.x;
    const int tx = t & 15, ty = t >> 4;
    const int am = t >> 3, ak4 = (t & 7) << 2;
    const int bk = t >> 4, bn4 = (t & 15) << 2;
    c0 = make_float4(0.f, 0.f, 0.f, 0.f);
    c1 = make_float4(0.f, 0.f, 0.f, 0.f);
    for (int kc = 0; kc < K; kc += 32) {
        float4 ga  = *(const float4*)(A + am * lda + kc + ak4);
        float4 gb0 = *(const float4*)(B + (kc + bk) * ldb + bn4);
        float4 gb1 = *(const float4*)(B + (kc + bk + 16) * ldb + bn4);
        __syncthreads();
        As[ak4 + 0][am] = ga.x; As[ak4 + 1][am] = ga.y;
        As[ak4 + 2][am] = ga.z; As[ak4 + 3][am] = ga.w;
        *(float4*)&Bs[bk][bn4]      = gb0;
        *(float4*)&Bs[bk + 16][bn4] = gb1;
        __syncthreads();
#pragma unroll
        for (int k = 0; k < 32; ++k) {
            float a0 = As[k][2 * ty], a1 = As[k][2 * ty + 1];
            float4 b4 = *(const float4*)&Bs[k][4 * tx];
            c0.x += a0 * b4.x; c0.y += a0 * b4.y; c0.z += a0 * b4.z; c0.w += a0 * b4.w;
            c1.x += a1 * b4.x; c1.y += a1 * b4.y; c1.z += a1 * b4.z; c1.w += a1 * b4.w;
        }
    }
}

// ---------------------------------------------------------------------------
// lastw job: 32x32 tile of W{1,2}p + mgW{1,2}. K=128.
// ---------------------------------------------------------------------------
__device__ __forceinline__ void lastw_job(
    int b, int fam, int i0, int j0,
    const float* W1, const float* mW1, const float* W2, const float* mW2,
    float* ws, float* out, float* smem) {
    const int t = threadIdx.x;
    float* wa = smem;
    float* wm = smem + 128;
    float (*Ls)[36] = (float(*)[36])(smem + 256);
    float (*Rs)[36] = (float(*)[36])(smem + 256 + 1152);
    __syncthreads();
    if (t < 128) {
        float lrv = ws[OFF_LR + b * 128 + t];
        wa[t] = ws[OFF_A + (b * 128 + 127) * 128 + t] * lrv;
        wm[t] = expf(ws[OFF_PM + b * 128 + 127] - ws[OFF_PM + b * 128 + t]) * lrv;
    }
    const float* left  = ws + (fam ? OFF_B2CAT : OFF_B1CAT) + b * 163840;
    const float* right = ws + (fam ? OFF_X2 : OFF_K) + b * 32768;
    float accA[2][2] = {{0.f, 0.f}, {0.f, 0.f}};
    float accM[2][2] = {{0.f, 0.f}, {0.f, 0.f}};
    int tx = t & 15, ty = t >> 4;
    int lrow = t >> 3, lc4 = (t & 7) << 2;
    for (int kc = 0; kc < 128; kc += 32) {
        __syncthreads();
        *(float4*)&Ls[lrow][lc4] = *(const float4*)(left + (kc + lrow) * 256 + i0 + lc4);
        *(float4*)&Rs[lrow][lc4] = *(const float4*)(right + (kc + lrow) * 256 + j0 + lc4);
        __syncthreads();
#pragma unroll
        for (int k = 0; k < 32; ++k) {
            float wak = wa[kc + k], wmk = wm[kc + k];
            float l0 = Ls[k][2 * ty], l1 = Ls[k][2 * ty + 1];
            float r0 = Rs[k][2 * tx], r1 = Rs[k][2 * tx + 1];
            float p00 = l0 * r0, p01 = l0 * r1, p10 = l1 * r0, p11 = l1 * r1;
            accA[0][0] += wak * p00; accA[0][1] += wak * p01;
            accA[1][0] += wak * p10; accA[1][1] += wak * p11;
            accM[0][0] += wmk * p00; accM[0][1] += wmk * p01;
            accM[1][0] += wmk * p10; accM[1][1] += wmk * p11;
        }
    }
    float c_last  = ws[OFF_C + b * 128 + 127];
    float wd_last = ws[OFF_WDCUM + b * 128 + 127];
    float mc_last = ws[OFF_MOMCUM + b * 128 + 127];
    const float* base1 = (fam ? W2 : W1) + b * 65536;
    const float* basem = (fam ? mW2 : mW1) + b * 65536;
    int opB = fam ? OUT_W2P : OUT_W1P;
    int omB = fam ? OUT_MGW2 : OUT_MGW1;
#pragma unroll
    for (int di = 0; di < 2; ++di)
#pragma unroll
        for (int dj = 0; dj < 2; ++dj) {
            int i = i0 + 2 * ty + di, j = j0 + 2 * tx + dj;
            float b1v = base1[i * 256 + j], bmv = basem[i * 256 + j];
            out[opB + (b * 256 + i) * 256 + j] = accA[di][dj] - c_last * bmv + wd_last * b1v;
            out[omB + (b * 256 + i) * 256 + j] = accM[di][dj] - mc_last * bmv;
        }
}

// ---------------------------------------------------------------------------
// The fused kernel: 256 blocks x 256 threads, 8 stages, 7 grid barriers.
// ---------------------------------------------------------------------------
__global__ __launch_bounds__(256) void fused_kernel(
    const float* x,
    const float* Wq, const float* bq,
    const float* Wk, const float* bk,
    const float* Wv, const float* bv,
    const float* Wlr, const float* blr,
    const float* Wm, const float* bm,
    const float* Wd, const float* bd,
    const float* W1, const float* b1,
    const float* W2, const float* b2,
    const float* mW1, const float* mb1,
    const float* mW2, const float* mb2,
    float* ws, float* out) {
    __shared__ float smem[3136];
    const int bid = blockIdx.x;
    const int t = threadIdx.x;
    const int tx = t & 15, ty = t >> 4;
    unsigned* bar = (unsigned*)(ws + OFF_BAR);

    // ======== R0: qkv GEMMs + scalar matvecs + weight transposes ========
    for (int j = bid; j < 616; j += NBLK) {
        __syncthreads();
        if (j < 96) {
            int which = j / 32, tile = j % 32, rowT = tile >> 2, colT = tile & 3;
            const float* Wp = which == 0 ? Wq : (which == 1 ? Wk : Wv);
            const float* bp = which == 0 ? bq : (which == 1 ? bk : bv);
            float4 c0, c1;
            gemm_tile(x + rowT * 32 * 256, 256, Wp + colT * 64, 256, 256, smem, c0, c1);
            float cc[2][4] = {{c0.x, c0.y, c0.z, c0.w}, {c1.x, c1.y, c1.z, c1.w}};
#pragma unroll
            for (int i = 0; i < 2; ++i)
#pragma unroll
                for (int jj = 0; jj < 4; ++jj) {
                    int m = rowT * 32 + 2 * ty + i;
                    int c = colT * 64 + 4 * tx + jj;
                    float v = cc[i][jj] + bp[c];
                    if (which == 0) {
                        ws[OFF_Q + m * 256 + c] = v;
                    } else if (which == 1) {
                        ws[OFF_K + m * 256 + c] = v;
                        ws[OFF_KT + (m >> 7) * 32768 + c * 128 + (m & 127)] = v;
                    } else {
                        ws[OFF_V + m * 256 + c] = v;
                    }
                }
        } else if (j < 104) {
            // scalar projections for 32 tokens: wave w handles 8 tokens
            int tk0 = (j - 96) * 32;
            float* ww = smem;
            ww[t] = Wlr[t]; ww[256 + t] = Wm[t]; ww[512 + t] = Wd[t];
            __syncthreads();
            int wv = t >> 6, lane = t & 63;
            float4 wl = *(const float4*)(ww + lane * 4);
            float4 wmv = *(const float4*)(ww + 256 + lane * 4);
            float4 wdv = *(const float4*)(ww + 512 + lane * 4);
            for (int i = 0; i < 8; ++i) {
                int tok = tk0 + wv * 8 + i;
                float4 xv = *(const float4*)(x + tok * 256 + lane * 4);
                float d0 = dot4(xv, wl), d1 = dot4(xv, wmv), d2 = dot4(xv, wdv);
#pragma unroll
                for (int off = 32; off > 0; off >>= 1) {
                    d0 += __shfl_down(d0, off);
                    d1 += __shfl_down(d1, off);
                    d2 += __shfl_down(d2, off);
                }
                if (lane == 0) {
                    ws[OFF_FC + tok] = d0;
                    ws[OFF_FC + 256 + tok] = d1;
                    ws[OFF_FC + 512 + tok] = d2;
                }
            }
        } else {
            // transpose W1/W2/mW1/mW2 32x32 tiles into CAT slots
            int j2 = j - 104;
            int mat = j2 >> 7, rem = j2 & 127, b = rem >> 6, tile = rem & 63;
            int r0 = (tile >> 3) * 32, c0 = (tile & 7) * 32;
            const float* src; float* dst;
            if (mat == 0)      { src = W1  + b * 65536; dst = ws + OFF_B1CAT + b * 163840 + 128 * 256; }
            else if (mat == 1) { src = W2  + b * 65536; dst = ws + OFF_B2CAT + b * 163840 + 128 * 256; }
            else if (mat == 2) { src = mW1 + b * 65536; dst = ws + OFF_B1CAT + b * 163840 + 384 * 256; }
            else               { src = mW2 + b * 65536; dst = ws + OFF_B2CAT + b * 163840 + 384 * 256; }
            float (*tl)[33] = (float(*)[33])smem;
            int ttx = t & 31, tty = t >> 5;
#pragma unroll
            for (int i = 0; i < 32; i += 8)
                tl[tty + i][ttx] = src[(r0 + tty + i) * 256 + (c0 + ttx)];
            __syncthreads();
#pragma unroll
            for (int i = 0; i < 32; i += 8)
                dst[(c0 + tty + i) * 256 + (r0 + ttx)] = tl[ttx][tty + i];
        }
    }
    grid_barrier(bar);

    // ======== R1: z1 GEMM -> X2/X2T/SILD; block 32 does the scans ========
    if (bid < 32) {
        int b = bid >> 4, tile = bid & 15, rowT = tile >> 2, colT = tile & 3;
        float4 c0, c1;
        gemm_tile(ws + OFF_K + b * 32768 + rowT * 32 * 256, 256,
                  ws + OFF_B1CAT + b * 163840 + 128 * 256 + colT * 64, 256, 256,
                  smem, c0, c1);
        float cc[2][4] = {{c0.x, c0.y, c0.z, c0.w}, {c1.x, c1.y, c1.z, c1.w}};
#pragma unroll
        for (int i = 0; i < 2; ++i)
#pragma unroll
            for (int jj = 0; jj < 4; ++jj) {
                int ml = rowT * 32 + 2 * ty + i;
                int n = colT * 64 + 4 * tx + jj;
                float z = cc[i][jj] + b1[b * 256 + n];
                float sg = 1.0f / (1.0f + expf(-z));
                float x2 = z * sg;
                int gm = b * 128 + ml;
                ws[OFF_X2 + gm * 256 + n] = x2;
                ws[OFF_X2T + b * 32768 + n * 128 + ml] = x2;
                ws[OFF_SILD + gm * 256 + n] = x2 + sg * (1.0f - x2);
            }
    } else if (bid == 32) {
        // both batches' scans (t = b*128 + i)
        int i = t & 127;
        float* sm = smem; float* sd = smem + 256; float* se = smem + 512;
        ws[OFF_LR + t] = softplus_f(ws[OFF_FC + t] + blr[0] + LR_SHIFT);
        float lm = -softplus_f(-(ws[OFF_FC + 256 + t] + bm[0]));
        float ld = -softplus_f(ws[OFF_FC + 512 + t] + bd[0]);
        sm[t] = lm; sd[t] = ld;
        __syncthreads();
        for (int off = 1; off < 128; off <<= 1) {
            float am_ = (i >= off) ? sm[t - off] : 0.0f;
            float ad_ = (i >= off) ? sd[t - off] : 0.0f;
            __syncthreads();
            sm[t] += am_; sd[t] += ad_;
            __syncthreads();
        }
        float pm = sm[t], pd = sd[t];
        ws[OFF_PM + t] = pm;
        ws[OFF_PD + t] = pd;
        ws[OFF_MOMCUM + t] = expf(pm);
        ws[OFF_WDCUM + t] = expf(pd);
        se[t] = expf(pm - pd);
        __syncthreads();
        for (int off = 1; off < 128; off <<= 1) {
            float a_ = (i >= off) ? se[t - off] : 0.0f;
            __syncthreads();
            se[t] += a_;
            __syncthreads();
        }
        ws[OFF_C + t] = expf(pd) * se[t];
    }
    grid_barrier(bar);

    // ======== R2: z2 GEMM -> GZ2; decay-matrix A + A1CAT q-slots ========
    for (int j = bid; j < 288; j += NBLK) {
        __syncthreads();
        if (j < 32) {
            int b = j >> 4, tile = j & 15, rowT = tile >> 2, colT = tile & 3;
            float4 c0, c1;
            gemm_tile(ws + OFF_X2 + b * 32768 + rowT * 32 * 256, 256,
                      ws + OFF_B2CAT + b * 163840 + 128 * 256 + colT * 64, 256, 256,
                      smem, c0, c1);
            float cc[2][4] = {{c0.x, c0.y, c0.z, c0.w}, {c1.x, c1.y, c1.z, c1.w}};
#pragma unroll
            for (int i = 0; i < 2; ++i)
#pragma unroll
                for (int jj = 0; jj < 4; ++jj) {
                    int ml = rowT * 32 + 2 * ty + i;
                    int n = colT * 64 + 4 * tx + jj;
                    int gm = b * 128 + ml;
                    float gz2 = cc[i][jj] + b2[b * 256 + n] - ws[OFF_V + gm * 256 + n];
                    ws[OFF_B2CAT + b * 163840 + ml * 256 + n] = gz2;
                }
        } else {
            int bl = j - 32, b = bl >> 7, l = bl & 127;
            if (t < 128) {
                float a = 0.0f;
                if (t <= l) {
                    const float* Pm = ws + OFF_PM + b * 128;
                    const float* Pd = ws + OFF_PD + b * 128;
                    float pdl = Pd[l], pmm = Pm[t], s = 0.0f;
                    for (int mm = t; mm <= l; ++mm)
                        s += expf((pdl - Pd[mm]) + (Pm[mm] - pmm));
                    a = s;
                }
                ws[OFF_A + bl * 128 + t] = a;
            }
            float q  = ws[OFF_Q + bl * 256 + t];
            float wdv = ws[OFF_WDCUM + b * 128 + l];
            float cl = ws[OFF_C + b * 128 + l];
            float* A1 = ws + OFF_A1CAT + b * 81920 + l * 640;
            A1[128 + t] = wdv * q;
            A1[384 + t] = -cl * q;
        }
    }
    grid_barrier(bar);

    // ======== R3: gx2 GEMM -> GZ1; lastw fam=1 (W2p/mgW2) ========
    if (bid < 32) {
        int b = bid >> 4, tile = bid & 15, rowT = tile >> 2, colT = tile & 3;
        float4 c0, c1;
        gemm_tile(ws + OFF_B2CAT + b * 163840 + rowT * 32 * 256, 256,
                  W2 + b * 65536 + colT * 64, 256, 256, smem, c0, c1);
        float cc[2][4] = {{c0.x, c0.y, c0.z, c0.w}, {c1.x, c1.y, c1.z, c1.w}};
#pragma unroll
        for (int i = 0; i < 2; ++i)
#pragma unroll
            for (int jj = 0; jj < 4; ++jj) {
                int ml = rowT * 32 + 2 * ty + i;
                int n = colT * 64 + 4 * tx + jj;
                int gm = b * 128 + ml;
                float gz1 = cc[i][jj] * ws[OFF_SILD + gm * 256 + n];
                ws[OFF_B1CAT + b * 163840 + ml * 256 + n] = gz1;
            }
    } else if (bid < 160) {
        int jdx = bid - 32, b = jdx >> 6, tile = jdx & 63;
        lastw_job(b, 1, (tile >> 3) * 32, (tile & 7) * 32,
                  W1, mW1, W2, mW2, ws, out, smem);
    }
    grid_barrier(bar);

    // ======== R4: score1 -> P1; lastw fam=0 (W1p/mgW1); lastb ========
    if (bid < 16) {
        int b = bid >> 3, rowT = (bid >> 1) & 3, colT = bid & 1;
        float* Acat = ws + OFF_A1CAT;
        if (colT * 64 > rowT * 32 + 31) {
#pragma unroll
            for (int i = 0; i < 2; ++i)
#pragma unroll
                for (int jj = 0; jj < 4; ++jj) {
                    int l = rowT * 32 + 2 * ty + i;
                    int mc = colT * 64 + 4 * tx + jj;
                    Acat[b * 81920 + l * 640 + mc] = 0.0f;
                }
        } else {
            float4 c0, c1;
            gemm_tile(ws + OFF_Q + b * 32768 + rowT * 32 * 256, 256,
                      ws + OFF_KT + b * 32768 + colT * 64, 128, 256, smem, c0, c1);
            float cc[2][4] = {{c0.x, c0.y, c0.z, c0.w}, {c1.x, c1.y, c1.z, c1.w}};
#pragma unroll
            for (int i = 0; i < 2; ++i)
#pragma unroll
                for (int jj = 0; jj < 4; ++jj) {
                    int l = rowT * 32 + 2 * ty + i;
                    int mc = colT * 64 + 4 * tx + jj;
                    float p = 0.0f;
                    if (mc <= l)
                        p = ws[OFF_A + (b * 128 + l) * 128 + mc] *
                            ws[OFF_LR + b * 128 + mc] * (1.0f + cc[i][jj]);
                    Acat[b * 81920 + l * 640 + mc] = p;
                }
        }
    } else if (bid < 144) {
        int jdx = bid - 16, b = jdx >> 6, tile = jdx & 63;
        lastw_job(b, 0, (tile >> 3) * 32, (tile & 7) * 32,
                  W1, mW1, W2, mW2, ws, out, smem);
    } else if (bid < 146) {
        int b = bid - 144;
        float* wa = smem; float* wm = smem + 128;
        if (t < 128) {
            float lrv = ws[OFF_LR + b * 128 + t];
            wa[t] = ws[OFF_A + (b * 128 + 127) * 128 + t] * lrv;
            wm[t] = expf(ws[OFF_PM + b * 128 + 127] - ws[OFF_PM + b * 128 + t]) * lrv;
        }
        __syncthreads();
        const float* gz1 = ws + OFF_B1CAT + b * 163840;
        const float* gz2 = ws + OFF_B2CAT + b * 163840;
        float sA1 = 0, sM1 = 0, sA2 = 0, sM2 = 0;
#pragma unroll 4
        for (int m = 0; m < 128; ++m) {
            float g1 = gz1[m * 256 + t], g2 = gz2[m * 256 + t];
            sA1 += wa[m] * g1; sM1 += wm[m] * g1;
            sA2 += wa[m] * g2; sM2 += wm[m] * g2;
        }
        float c_last  = ws[OFF_C + b * 128 + 127];
        float wd_last = ws[OFF_WDCUM + b * 128 + 127];
        float mc_last = ws[OFF_MOMCUM + b * 128 + 127];
        out[OUT_B1P + b * 256 + t]  = sA1 - c_last * mb1[b * 256 + t] + wd_last * b1[b * 256 + t];
        out[OUT_MGB1 + b * 256 + t] = sM1 - mc_last * mb1[b * 256 + t];
        out[OUT_B2P + b * 256 + t]  = sA2 - c_last * mb2[b * 256 + t] + wd_last * b2[b * 256 + t];
        out[OUT_MGB2 + b * 256 + t] = sM2 - mc_last * mb2[b * 256 + t];
    }
    grid_barrier(bar);

    // ======== R5: zq1 (K=640) -> XQ + A2CAT slots ========
    if (bid < 32) {
        int b = bid >> 4, tile = bid & 15, rowT = tile >> 2, colT = tile & 3;
        float4 c0, c1;
        gemm_tile(ws + OFF_A1CAT + b * 81920 + rowT * 32 * 640, 640,
                  ws + OFF_B1CAT + b * 163840 + colT * 64, 256, 640, smem, c0, c1);
        float cc[2][4] = {{c0.x, c0.y, c0.z, c0.w}, {c1.x, c1.y, c1.z, c1.w}};
#pragma unroll
        for (int i = 0; i < 2; ++i)
#pragma unroll
            for (int jj = 0; jj < 4; ++jj) {
                int ml = rowT * 32 + 2 * ty + i;
                int n = colT * 64 + 4 * tx + jj;
                float cl = ws[OFF_C + b * 128 + ml];
                float wdv = ws[OFF_WDCUM + b * 128 + ml];
                float z = cc[i][jj] + wdv * b1[b * 256 + n] - cl * mb1[b * 256 + n];
                float sg = 1.0f / (1.0f + expf(-z));
                float xq = z * sg;
                ws[OFF_XQ + (b * 128 + ml) * 256 + n] = xq;
                float* A2 = ws + OFF_A2CAT + b * 81920 + ml * 640;
                A2[128 + n] = wdv * xq;
                A2[384 + n] = -cl * xq;
            }
    }
    grid_barrier(bar);

    // ======== R6: score2 -> P2 ========
    if (bid < 16) {
        int b = bid >> 3, rowT = (bid >> 1) & 3, colT = bid & 1;
        float* Acat = ws + OFF_A2CAT;
        if (colT * 64 > rowT * 32 + 31) {
#pragma unroll
            for (int i = 0; i < 2; ++i)
#pragma unroll
                for (int jj = 0; jj < 4; ++jj) {
                    int l = rowT * 32 + 2 * ty + i;
                    int mc = colT * 64 + 4 * tx + jj;
                    Acat[b * 81920 + l * 640 + mc] = 0.0f;
                }
        } else {
            float4 c0, c1;
            gemm_tile(ws + OFF_XQ + b * 32768 + rowT * 32 * 256, 256,
                      ws + OFF_X2T + b * 32768 + colT * 64, 128, 256, smem, c0, c1);
            float cc[2][4] = {{c0.x, c0.y, c0.z, c0.w}, {c1.x, c1.y, c1.z, c1.w}};
#pragma unroll
            for (int i = 0; i < 2; ++i)
#pragma unroll
                for (int jj = 0; jj < 4; ++jj) {
                    int l = rowT * 32 + 2 * ty + i;
                    int mc = colT * 64 + 4 * tx + jj;
                    float p = 0.0f;
                    if (mc <= l)
                        p = ws[OFF_A + (b * 128 + l) * 128 + mc] *
                            ws[OFF_LR + b * 128 + mc] * (1.0f + cc[i][jj]);
                    Acat[b * 81920 + l * 640 + mc] = p;
                }
        }
    }
    grid_barrier(bar);

    // ======== R7: zq2 (K=640) -> out ========
    if (bid < 32) {
        int b = bid >> 4, tile = bid & 15, rowT = tile >> 2, colT = tile & 3;
        float4 c0, c1;
        gemm_tile(ws + OFF_A2CAT + b * 81920 + rowT * 32 * 640, 640,
                  ws + OFF_B2CAT + b * 163840 + colT * 64, 256, 640, smem, c0, c1);
        float cc[2][4] = {{c0.x, c0.y, c0.z, c0.w}, {c1.x, c1.y, c1.z, c1.w}};
#pragma unroll
        for (int i = 0; i < 2; ++i)
#pragma unroll
            for (int jj = 0; jj < 4; ++jj) {
                int ml = rowT * 32 + 2 * ty + i;
                int n = colT * 64 + 4 * tx + jj;
                float cl = ws[OFF_C + b * 128 + ml];
                float wdv = ws[OFF_WDCUM + b * 128 + ml];
                out[OUT_ZQ2 + (b * 128 + ml) * 256 + n] =
                    cc[i][jj] + wdv * b2[b * 256 + n] - cl * mb2[b * 256 + n];
            }
    }
}

// ---------------------------------------------------------------------------
__global__ void init_kernel(unsigned* bar) {
    bar[0] = 0u;
    bar[1] = 0u;
}

// ---------------------------------------------------------------------------
extern "C" void kernel_launch(void* const* d_in, const int* in_sizes, int n_in,
                              void* d_out, int out_size, void* d_ws, size_t ws_size,
                              hipStream_t stream) {
    const float* x   = (const float*)d_in[0];
    const float* Wq  = (const float*)d_in[1];
    const float* bq  = (const float*)d_in[2];
    const float* Wk  = (const float*)d_in[3];
    const float* bk  = (const float*)d_in[4];
    const float* Wv  = (const float*)d_in[5];
    const float* bv  = (const float*)d_in[6];
    const float* Wlr = (const float*)d_in[7];
    const float* blr = (const float*)d_in[8];
    const float* Wm  = (const float*)d_in[9];
    const float* bm  = (const float*)d_in[10];
    const float* Wd  = (const float*)d_in[11];
    const float* bd  = (const float*)d_in[12];
    const float* W1  = (const float*)d_in[13];
    const float* b1  = (const float*)d_in[14];
    const float* W2  = (const float*)d_in[15];
    const float* b2  = (const float*)d_in[16];
    const float* mW1 = (const float*)d_in[17];
    const float* mb1 = (const float*)d_in[18];
    const float* mW2 = (const float*)d_in[19];
    const float* mb2 = (const float*)d_in[20];
    float* ws  = (float*)d_ws;
    float* out = (float*)d_out;

    init_kernel<<<1, 1, 0, stream>>>((unsigned*)(ws + OFF_BAR));
    fused_kernel<<<NBLK, 256, 0, stream>>>(
        x, Wq, bq, Wk, bk, Wv, bv, Wlr, blr, Wm, bm, Wd, bd,
        W1, b1, W2, b2, mW1, mb1, mW2, mb2, ws, out);
}

// Round 5
// 295.810 us; speedup vs baseline: 1.6738x; 1.6738x over previous
//
#include <hip/hip_runtime.h>
#include <math.h>

// Problem constants
constexpr int Bn = 2, Ln = 128;

// log(expm1(0.01))
#define LR_SHIFT (-4.6001660040607144f)

// ---------------------------------------------------------------------------
// Workspace layout (floats)
// ---------------------------------------------------------------------------
constexpr int OFF_Q      = 0;        // [256 tok][256]
constexpr int OFF_K      = 65536;    // [256 tok][256]
constexpr int OFF_V      = 131072;   // [256 tok][256]
constexpr int OFF_X2     = 196608;   // [256 tok][256]
constexpr int OFF_SILD   = 262144;   // [256 tok][256] silu_backward(Z1)
constexpr int OFF_XQ     = 327680;   // [256 tok][256]
constexpr int OFF_KT     = 393216;   // [B][256 d][128 l]
constexpr int OFF_X2T    = 458752;   // [B][256 h][128 l]
constexpr int OFF_A      = 524288;   // [B][128 l][128 m]  A = Dm@M
constexpr int OFF_B1CAT  = 557056;   // [B][640][256]: rows 0-127 GZ1, 128-383 W1t, 384-639 mW1t
constexpr int OFF_B2CAT  = 884736;   // [B][640][256]: rows 0-127 GZ2, 128-383 W2t, 384-639 mW2t
constexpr int OFF_A1CAT  = 1212416;  // [B][128 l][640]: cols 0-127 P1, 128-383 wd*q, 384-639 -c*q
constexpr int OFF_A2CAT  = 1376256;  // [B][128 l][640]
constexpr int OFF_FC     = 1540096;  // [3][256] raw lr/mom/wd projections
constexpr int OFF_LR     = 1540864;  // [B][128]
constexpr int OFF_PM     = 1541120;  // [B][128]
constexpr int OFF_PD     = 1541376;  // [B][128]
constexpr int OFF_MOMCUM = 1541632;  // [B][128]
constexpr int OFF_WDCUM  = 1541888;  // [B][128]
constexpr int OFF_C      = 1542144;  // [B][128]
constexpr int OFF_BAR    = 1542656;  // 1024 unsigned words (4 KB) barrier region

// Barrier word offsets (within bar region, unsigned):
//   slots:    g*32 + idx      (g = bid&7, idx = bid>>3)   words 0..255
//   rootslot: 320 + g                                      words 320..327
//   rootgen:  384
//   grpgen:   448 + g*32                                   words 448..672

// Output offsets (floats), tuple order
constexpr int OUT_ZQ2  = 0;
constexpr int OUT_W1P  = 65536;
constexpr int OUT_B1P  = 196608;
constexpr int OUT_W2P  = 197120;
constexpr int OUT_B2P  = 328192;
constexpr int OUT_MGW1 = 328704;
constexpr int OUT_MGB1 = 459776;
constexpr int OUT_MGW2 = 460288;
constexpr int OUT_MGB2 = 591360;

constexpr int NBLK = 256;

__device__ __forceinline__ float softplus_f(float z) {
    return fmaxf(z, 0.0f) + log1pf(expf(-fabsf(z)));
}

__device__ __forceinline__ float dot4(float4 a, float4 b) {
    return a.x * b.x + a.y * b.y + a.z * b.z + a.w * b.w;
}

// ---------------------------------------------------------------------------
// Hierarchical RMW-free grid barrier. Per-block arrival slots (no atomic
// contention), 8 group leaders poll 32 slots with 32 lanes, root polls 8
// group flags, broadcast via per-group gen words on separate cachelines.
// All 256 blocks are co-resident (capacity >= 2 blocks/CU at 12.5KB LDS,
// 68 VGPR), so spinning is deadlock-free.
// ---------------------------------------------------------------------------
__device__ __forceinline__ void grid_barrier(unsigned* bar, int bid, unsigned epoch) {
    __syncthreads();
    const int t = threadIdx.x;
    const int g = bid & 7, idx = bid >> 3;
    if (t == 0) {
        __threadfence();  // release: flush this block's data writes agent-wide
        __hip_atomic_store(&bar[g * 32 + idx], epoch, __ATOMIC_RELAXED,
                           __HIP_MEMORY_SCOPE_AGENT);
    }
    if (bid < 8) {
        // leader for group g == bid (its own slot is idx 0 of this group)
        if (t < 32) {
            while (__hip_atomic_load(&bar[bid * 32 + t], __ATOMIC_RELAXED,
                                     __HIP_MEMORY_SCOPE_AGENT) < epoch)
                __builtin_amdgcn_s_sleep(1);
        }
        if (t == 0)
            __hip_atomic_store(&bar[320 + bid], epoch, __ATOMIC_RELAXED,
                               __HIP_MEMORY_SCOPE_AGENT);
        if (bid == 0) {
            if (t < 8) {
                while (__hip_atomic_load(&bar[320 + t], __ATOMIC_RELAXED,
                                         __HIP_MEMORY_SCOPE_AGENT) < epoch)
                    __builtin_amdgcn_s_sleep(1);
            }
            if (t == 0)
                __hip_atomic_store(&bar[384], epoch, __ATOMIC_RELAXED,
                                   __HIP_MEMORY_SCOPE_AGENT);
        }
        if (t == 0) {
            while (__hip_atomic_load(&bar[384], __ATOMIC_RELAXED,
                                     __HIP_MEMORY_SCOPE_AGENT) < epoch)
                __builtin_amdgcn_s_sleep(1);
            __hip_atomic_store(&bar[448 + bid * 32], epoch, __ATOMIC_RELAXED,
                               __HIP_MEMORY_SCOPE_AGENT);
        }
    }
    if (t == 0) {
        while (__hip_atomic_load(&bar[448 + g * 32], __ATOMIC_RELAXED,
                                 __HIP_MEMORY_SCOPE_AGENT) < epoch)
            __builtin_amdgcn_s_sleep(1);
        __threadfence();  // acquire: invalidate stale caches before reading peers' data
    }
    __syncthreads();
}

// ---------------------------------------------------------------------------
// GEMM tile: 32x64 output, 256 threads, 2x4 register tile, KC=32.
// A: [32 rows][K] (lda), B: [K][64 cols] (ldb). smem >= 3136 floats.
// ---------------------------------------------------------------------------
__device__ __forceinline__ void gemm_tile(
    const float* A, int lda, const float* B, int ldb, int K,
    float* smem, float4& c0, float4& c1) {
    float (*As)[34] = (float(*)[34])smem;            // [k][m]
    float (*Bs)[64] = (float(*)[64])(smem + 1088);   // [k][n]
    const int t = threadIdx.x;
    const int tx = t & 15, ty = t >> 4;
    const int am = t >> 3, ak4 = (t & 7) << 2;
    const int bk = t >> 4, bn4 = (t & 15) << 2;
    c0 = make_float4(0.f, 0.f, 0.f, 0.f);
    c1 = make_float4(0.f, 0.f, 0.f, 0.f);
    for (int kc = 0; kc < K; kc += 32) {
        float4 ga  = *(const float4*)(A + am * lda + kc + ak4);
        float4 gb0 = *(const float4*)(B + (kc + bk) * ldb + bn4);
        float4 gb1 = *(const float4*)(B + (kc + bk + 16) * ldb + bn4);
        __syncthreads();
        As[ak4 + 0][am] = ga.x; As[ak4 + 1][am] = ga.y;
        As[ak4 + 2][am] = ga.z; As[ak4 + 3][am] = ga.w;
        *(float4*)&Bs[bk][bn4]      = gb0;
        *(float4*)&Bs[bk + 16][bn4] = gb1;
        __syncthreads();
#pragma unroll
        for (int k = 0; k < 32; ++k) {
            float a0 = As[k][2 * ty], a1 = As[k][2 * ty + 1];
            float4 b4 = *(const float4*)&Bs[k][4 * tx];
            c0.x += a0 * b4.x; c0.y += a0 * b4.y; c0.z += a0 * b4.z; c0.w += a0 * b4.w;
            c1.x += a1 * b4.x; c1.y += a1 * b4.y; c1.z += a1 * b4.z; c1.w += a1 * b4.w;
        }
    }
}

// ---------------------------------------------------------------------------
// lastw job: 32x32 tile of W{1,2}p + mgW{1,2}. K=128.
// ---------------------------------------------------------------------------
__device__ __forceinline__ void lastw_job(
    int b, int fam, int i0, int j0,
    const float* W1, const float* mW1, const float* W2, const float* mW2,
    float* ws, float* out, float* smem) {
    const int t = threadIdx.x;
    float* wa = smem;
    float* wm = smem + 128;
    float (*Ls)[36] = (float(*)[36])(smem + 256);
    float (*Rs)[36] = (float(*)[36])(smem + 256 + 1152);
    __syncthreads();
    if (t < 128) {
        float lrv = ws[OFF_LR + b * 128 + t];
        wa[t] = ws[OFF_A + (b * 128 + 127) * 128 + t] * lrv;
        wm[t] = expf(ws[OFF_PM + b * 128 + 127] - ws[OFF_PM + b * 128 + t]) * lrv;
    }
    const float* left  = ws + (fam ? OFF_B2CAT : OFF_B1CAT) + b * 163840;
    const float* right = ws + (fam ? OFF_X2 : OFF_K) + b * 32768;
    float accA[2][2] = {{0.f, 0.f}, {0.f, 0.f}};
    float accM[2][2] = {{0.f, 0.f}, {0.f, 0.f}};
    int tx = t & 15, ty = t >> 4;
    int lrow = t >> 3, lc4 = (t & 7) << 2;
    for (int kc = 0; kc < 128; kc += 32) {
        __syncthreads();
        *(float4*)&Ls[lrow][lc4] = *(const float4*)(left + (kc + lrow) * 256 + i0 + lc4);
        *(float4*)&Rs[lrow][lc4] = *(const float4*)(right + (kc + lrow) * 256 + j0 + lc4);
        __syncthreads();
#pragma unroll
        for (int k = 0; k < 32; ++k) {
            float wak = wa[kc + k], wmk = wm[kc + k];
            float l0 = Ls[k][2 * ty], l1 = Ls[k][2 * ty + 1];
            float r0 = Rs[k][2 * tx], r1 = Rs[k][2 * tx + 1];
            float p00 = l0 * r0, p01 = l0 * r1, p10 = l1 * r0, p11 = l1 * r1;
            accA[0][0] += wak * p00; accA[0][1] += wak * p01;
            accA[1][0] += wak * p10; accA[1][1] += wak * p11;
            accM[0][0] += wmk * p00; accM[0][1] += wmk * p01;
            accM[1][0] += wmk * p10; accM[1][1] += wmk * p11;
        }
    }
    float c_last  = ws[OFF_C + b * 128 + 127];
    float wd_last = ws[OFF_WDCUM + b * 128 + 127];
    float mc_last = ws[OFF_MOMCUM + b * 128 + 127];
    const float* base1 = (fam ? W2 : W1) + b * 65536;
    const float* basem = (fam ? mW2 : mW1) + b * 65536;
    int opB = fam ? OUT_W2P : OUT_W1P;
    int omB = fam ? OUT_MGW2 : OUT_MGW1;
#pragma unroll
    for (int di = 0; di < 2; ++di)
#pragma unroll
        for (int dj = 0; dj < 2; ++dj) {
            int i = i0 + 2 * ty + di, j = j0 + 2 * tx + dj;
            float b1v = base1[i * 256 + j], bmv = basem[i * 256 + j];
            out[opB + (b * 256 + i) * 256 + j] = accA[di][dj] - c_last * bmv + wd_last * b1v;
            out[omB + (b * 256 + i) * 256 + j] = accM[di][dj] - mc_last * bmv;
        }
}

// ---------------------------------------------------------------------------
// The fused kernel: 256 blocks x 256 threads, 6 stages, 5 grid barriers.
// ---------------------------------------------------------------------------
__global__ __launch_bounds__(256) void fused_kernel(
    const float* x,
    const float* Wq, const float* bq,
    const float* Wk, const float* bk,
    const float* Wv, const float* bv,
    const float* Wlr, const float* blr,
    const float* Wm, const float* bm,
    const float* Wd, const float* bd,
    const float* W1, const float* b1,
    const float* W2, const float* b2,
    const float* mW1, const float* mb1,
    const float* mW2, const float* mb2,
    float* ws, float* out) {
    __shared__ float smem[3136];
    const int bid = blockIdx.x;
    const int t = threadIdx.x;
    const int tx = t & 15, ty = t >> 4;
    unsigned* bar = (unsigned*)(ws + OFF_BAR);

    // ======== S0: qkv GEMMs + scalar matvecs + weight transposes ========
    for (int j = bid; j < 616; j += NBLK) {
        __syncthreads();
        if (j < 96) {
            int which = j / 32, tile = j % 32, rowT = tile >> 2, colT = tile & 3;
            const float* Wp = which == 0 ? Wq : (which == 1 ? Wk : Wv);
            const float* bp = which == 0 ? bq : (which == 1 ? bk : bv);
            float4 c0, c1;
            gemm_tile(x + rowT * 32 * 256, 256, Wp + colT * 64, 256, 256, smem, c0, c1);
            float cc[2][4] = {{c0.x, c0.y, c0.z, c0.w}, {c1.x, c1.y, c1.z, c1.w}};
#pragma unroll
            for (int i = 0; i < 2; ++i)
#pragma unroll
                for (int jj = 0; jj < 4; ++jj) {
                    int m = rowT * 32 + 2 * ty + i;
                    int c = colT * 64 + 4 * tx + jj;
                    float v = cc[i][jj] + bp[c];
                    if (which == 0) {
                        ws[OFF_Q + m * 256 + c] = v;
                    } else if (which == 1) {
                        ws[OFF_K + m * 256 + c] = v;
                        ws[OFF_KT + (m >> 7) * 32768 + c * 128 + (m & 127)] = v;
                    } else {
                        ws[OFF_V + m * 256 + c] = v;
                    }
                }
        } else if (j < 104) {
            // scalar projections for 32 tokens: wave w handles 8 tokens
            int tk0 = (j - 96) * 32;
            float* ww = smem;
            ww[t] = Wlr[t]; ww[256 + t] = Wm[t]; ww[512 + t] = Wd[t];
            __syncthreads();
            int wv = t >> 6, lane = t & 63;
            float4 wl = *(const float4*)(ww + lane * 4);
            float4 wmv = *(const float4*)(ww + 256 + lane * 4);
            float4 wdv = *(const float4*)(ww + 512 + lane * 4);
            for (int i = 0; i < 8; ++i) {
                int tok = tk0 + wv * 8 + i;
                float4 xv = *(const float4*)(x + tok * 256 + lane * 4);
                float d0 = dot4(xv, wl), d1 = dot4(xv, wmv), d2 = dot4(xv, wdv);
#pragma unroll
                for (int off = 32; off > 0; off >>= 1) {
                    d0 += __shfl_down(d0, off);
                    d1 += __shfl_down(d1, off);
                    d2 += __shfl_down(d2, off);
                }
                if (lane == 0) {
                    ws[OFF_FC + tok] = d0;
                    ws[OFF_FC + 256 + tok] = d1;
                    ws[OFF_FC + 512 + tok] = d2;
                }
            }
        } else {
            // transpose W1/W2/mW1/mW2 32x32 tiles into CAT slots
            int j2 = j - 104;
            int mat = j2 >> 7, rem = j2 & 127, b = rem >> 6, tile = rem & 63;
            int r0 = (tile >> 3) * 32, c0 = (tile & 7) * 32;
            const float* src; float* dst;
            if (mat == 0)      { src = W1  + b * 65536; dst = ws + OFF_B1CAT + b * 163840 + 128 * 256; }
            else if (mat == 1) { src = W2  + b * 65536; dst = ws + OFF_B2CAT + b * 163840 + 128 * 256; }
            else if (mat == 2) { src = mW1 + b * 65536; dst = ws + OFF_B1CAT + b * 163840 + 384 * 256; }
            else               { src = mW2 + b * 65536; dst = ws + OFF_B2CAT + b * 163840 + 384 * 256; }
            float (*tl)[33] = (float(*)[33])smem;
            int ttx = t & 31, tty = t >> 5;
#pragma unroll
            for (int i = 0; i < 32; i += 8)
                tl[tty + i][ttx] = src[(r0 + tty + i) * 256 + (c0 + ttx)];
            __syncthreads();
#pragma unroll
            for (int i = 0; i < 32; i += 8)
                dst[(c0 + tty + i) * 256 + (r0 + ttx)] = tl[ttx][tty + i];
        }
    }
    grid_barrier(bar, bid, 1u);

    // ======== S1: z1 GEMM -> X2/X2T/SILD; block 32 does the scans ========
    if (bid < 32) {
        int b = bid >> 4, tile = bid & 15, rowT = tile >> 2, colT = tile & 3;
        float4 c0, c1;
        gemm_tile(ws + OFF_K + b * 32768 + rowT * 32 * 256, 256,
                  ws + OFF_B1CAT + b * 163840 + 128 * 256 + colT * 64, 256, 256,
                  smem, c0, c1);
        float cc[2][4] = {{c0.x, c0.y, c0.z, c0.w}, {c1.x, c1.y, c1.z, c1.w}};
#pragma unroll
        for (int i = 0; i < 2; ++i)
#pragma unroll
            for (int jj = 0; jj < 4; ++jj) {
                int ml = rowT * 32 + 2 * ty + i;
                int n = colT * 64 + 4 * tx + jj;
                float z = cc[i][jj] + b1[b * 256 + n];
                float sg = 1.0f / (1.0f + expf(-z));
                float x2 = z * sg;
                int gm = b * 128 + ml;
                ws[OFF_X2 + gm * 256 + n] = x2;
                ws[OFF_X2T + b * 32768 + n * 128 + ml] = x2;
                ws[OFF_SILD + gm * 256 + n] = x2 + sg * (1.0f - x2);
            }
    } else if (bid == 32) {
        // both batches' scans (t = b*128 + i)
        int i = t & 127;
        float* sm = smem; float* sd = smem + 256; float* se = smem + 512;
        ws[OFF_LR + t] = softplus_f(ws[OFF_FC + t] + blr[0] + LR_SHIFT);
        float lm = -softplus_f(-(ws[OFF_FC + 256 + t] + bm[0]));
        float ld = -softplus_f(ws[OFF_FC + 512 + t] + bd[0]);
        sm[t] = lm; sd[t] = ld;
        __syncthreads();
        for (int off = 1; off < 128; off <<= 1) {
            float am_ = (i >= off) ? sm[t - off] : 0.0f;
            float ad_ = (i >= off) ? sd[t - off] : 0.0f;
            __syncthreads();
            sm[t] += am_; sd[t] += ad_;
            __syncthreads();
        }
        float pm = sm[t], pd = sd[t];
        ws[OFF_PM + t] = pm;
        ws[OFF_PD + t] = pd;
        ws[OFF_MOMCUM + t] = expf(pm);
        ws[OFF_WDCUM + t] = expf(pd);
        se[t] = expf(pm - pd);
        __syncthreads();
        for (int off = 1; off < 128; off <<= 1) {
            float a_ = (i >= off) ? se[t - off] : 0.0f;
            __syncthreads();
            se[t] += a_;
            __syncthreads();
        }
        ws[OFF_C + t] = expf(pd) * se[t];
    }
    grid_barrier(bar, bid, 2u);

    // ======== S2: z2 GEMM -> GZ2; decay-matrix A + A1CAT q-slots ========
    for (int j = bid; j < 288; j += NBLK) {
        __syncthreads();
        if (j < 32) {
            int b = j >> 4, tile = j & 15, rowT = tile >> 2, colT = tile & 3;
            float4 c0, c1;
            gemm_tile(ws + OFF_X2 + b * 32768 + rowT * 32 * 256, 256,
                      ws + OFF_B2CAT + b * 163840 + 128 * 256 + colT * 64, 256, 256,
                      smem, c0, c1);
            float cc[2][4] = {{c0.x, c0.y, c0.z, c0.w}, {c1.x, c1.y, c1.z, c1.w}};
#pragma unroll
            for (int i = 0; i < 2; ++i)
#pragma unroll
                for (int jj = 0; jj < 4; ++jj) {
                    int ml = rowT * 32 + 2 * ty + i;
                    int n = colT * 64 + 4 * tx + jj;
                    int gm = b * 128 + ml;
                    float gz2 = cc[i][jj] + b2[b * 256 + n] - ws[OFF_V + gm * 256 + n];
                    ws[OFF_B2CAT + b * 163840 + ml * 256 + n] = gz2;
                }
        } else {
            int bl = j - 32, b = bl >> 7, l = bl & 127;
            if (t < 128) {
                float a = 0.0f;
                if (t <= l) {
                    const float* Pm = ws + OFF_PM + b * 128;
                    const float* Pd = ws + OFF_PD + b * 128;
                    float pdl = Pd[l], pmm = Pm[t], s = 0.0f;
                    for (int mm = t; mm <= l; ++mm)
                        s += expf((pdl - Pd[mm]) + (Pm[mm] - pmm));
                    a = s;
                }
                ws[OFF_A + bl * 128 + t] = a;
            }
            float q  = ws[OFF_Q + bl * 256 + t];
            float wdv = ws[OFF_WDCUM + b * 128 + l];
            float cl = ws[OFF_C + b * 128 + l];
            float* A1 = ws + OFF_A1CAT + b * 81920 + l * 640;
            A1[128 + t] = wdv * q;
            A1[384 + t] = -cl * q;
        }
    }
    grid_barrier(bar, bid, 3u);

    // ======== S3: gx2 GEMM -> GZ1; lastw fam=1 (W2p/mgW2) ========
    if (bid < 32) {
        int b = bid >> 4, tile = bid & 15, rowT = tile >> 2, colT = tile & 3;
        float4 c0, c1;
        gemm_tile(ws + OFF_B2CAT + b * 163840 + rowT * 32 * 256, 256,
                  W2 + b * 65536 + colT * 64, 256, 256, smem, c0, c1);
        float cc[2][4] = {{c0.x, c0.y, c0.z, c0.w}, {c1.x, c1.y, c1.z, c1.w}};
#pragma unroll
        for (int i = 0; i < 2; ++i)
#pragma unroll
            for (int jj = 0; jj < 4; ++jj) {
                int ml = rowT * 32 + 2 * ty + i;
                int n = colT * 64 + 4 * tx + jj;
                int gm = b * 128 + ml;
                float gz1 = cc[i][jj] * ws[OFF_SILD + gm * 256 + n];
                ws[OFF_B1CAT + b * 163840 + ml * 256 + n] = gz1;
            }
    } else if (bid < 160) {
        int jdx = bid - 32, b = jdx >> 6, tile = jdx & 63;
        lastw_job(b, 1, (tile >> 3) * 32, (tile & 7) * 32,
                  W1, mW1, W2, mW2, ws, out, smem);
    }
    grid_barrier(bar, bid, 4u);

    // ======== S4: zq1 (score1 inline, K=640); lastw fam=0; lastb ========
    if (bid < 32) {
        int b = bid >> 4, tile = bid & 15, rowT = tile >> 2, colT = tile & 3;
        // score part: this block computes P1 rows [rowT*32,+32), cols 0..127
        // (the 4 colT blocks per rowT produce bit-identical copies; benign)
        for (int c2 = 0; c2 < 2; ++c2) {
            __syncthreads();
            if (c2 * 64 > rowT * 32 + 31) {
                for (int e = t; e < 2048; e += 256) {
                    int l = rowT * 32 + (e >> 6), mc = c2 * 64 + (e & 63);
                    ws[OFF_A1CAT + b * 81920 + l * 640 + mc] = 0.0f;
                }
            } else {
                float4 c0, c1;
                gemm_tile(ws + OFF_Q + b * 32768 + rowT * 32 * 256, 256,
                          ws + OFF_KT + b * 32768 + c2 * 64, 128, 256, smem, c0, c1);
                float cc[2][4] = {{c0.x, c0.y, c0.z, c0.w}, {c1.x, c1.y, c1.z, c1.w}};
#pragma unroll
                for (int i = 0; i < 2; ++i)
#pragma unroll
                    for (int jj = 0; jj < 4; ++jj) {
                        int l = rowT * 32 + 2 * ty + i;
                        int mc = c2 * 64 + 4 * tx + jj;
                        float p = 0.0f;
                        if (mc <= l)
                            p = ws[OFF_A + (b * 128 + l) * 128 + mc] *
                                ws[OFF_LR + b * 128 + mc] * (1.0f + cc[i][jj]);
                        ws[OFF_A1CAT + b * 81920 + l * 640 + mc] = p;
                    }
            }
        }
        __threadfence_block();
        __syncthreads();
        float4 c0, c1;
        gemm_tile(ws + OFF_A1CAT + b * 81920 + rowT * 32 * 640, 640,
                  ws + OFF_B1CAT + b * 163840 + colT * 64, 256, 640, smem, c0, c1);
        float cc[2][4] = {{c0.x, c0.y, c0.z, c0.w}, {c1.x, c1.y, c1.z, c1.w}};
#pragma unroll
        for (int i = 0; i < 2; ++i)
#pragma unroll
            for (int jj = 0; jj < 4; ++jj) {
                int ml = rowT * 32 + 2 * ty + i;
                int n = colT * 64 + 4 * tx + jj;
                float cl = ws[OFF_C + b * 128 + ml];
                float wdv = ws[OFF_WDCUM + b * 128 + ml];
                float z = cc[i][jj] + wdv * b1[b * 256 + n] - cl * mb1[b * 256 + n];
                float sg = 1.0f / (1.0f + expf(-z));
                float xq = z * sg;
                ws[OFF_XQ + (b * 128 + ml) * 256 + n] = xq;
                float* A2 = ws + OFF_A2CAT + b * 81920 + ml * 640;
                A2[128 + n] = wdv * xq;
                A2[384 + n] = -cl * xq;
            }
    } else if (bid < 160) {
        int jdx = bid - 32, b = jdx >> 6, tile = jdx & 63;
        lastw_job(b, 0, (tile >> 3) * 32, (tile & 7) * 32,
                  W1, mW1, W2, mW2, ws, out, smem);
    } else if (bid < 162) {
        int b = bid - 160;
        float* wa = smem; float* wm = smem + 128;
        if (t < 128) {
            float lrv = ws[OFF_LR + b * 128 + t];
            wa[t] = ws[OFF_A + (b * 128 + 127) * 128 + t] * lrv;
            wm[t] = expf(ws[OFF_PM + b * 128 + 127] - ws[OFF_PM + b * 128 + t]) * lrv;
        }
        __syncthreads();
        const float* gz1 = ws + OFF_B1CAT + b * 163840;
        const float* gz2 = ws + OFF_B2CAT + b * 163840;
        float sA1 = 0, sM1 = 0, sA2 = 0, sM2 = 0;
#pragma unroll 4
        for (int m = 0; m < 128; ++m) {
            float g1 = gz1[m * 256 + t], g2 = gz2[m * 256 + t];
            sA1 += wa[m] * g1; sM1 += wm[m] * g1;
            sA2 += wa[m] * g2; sM2 += wm[m] * g2;
        }
        float c_last  = ws[OFF_C + b * 128 + 127];
        float wd_last = ws[OFF_WDCUM + b * 128 + 127];
        float mc_last = ws[OFF_MOMCUM + b * 128 + 127];
        out[OUT_B1P + b * 256 + t]  = sA1 - c_last * mb1[b * 256 + t] + wd_last * b1[b * 256 + t];
        out[OUT_MGB1 + b * 256 + t] = sM1 - mc_last * mb1[b * 256 + t];
        out[OUT_B2P + b * 256 + t]  = sA2 - c_last * mb2[b * 256 + t] + wd_last * b2[b * 256 + t];
        out[OUT_MGB2 + b * 256 + t] = sM2 - mc_last * mb2[b * 256 + t];
    }
    grid_barrier(bar, bid, 5u);

    // ======== S5: zq2 (score2 inline, K=640) -> out ========
    if (bid < 32) {
        int b = bid >> 4, tile = bid & 15, rowT = tile >> 2, colT = tile & 3;
        for (int c2 = 0; c2 < 2; ++c2) {
            __syncthreads();
            if (c2 * 64 > rowT * 32 + 31) {
                for (int e = t; e < 2048; e += 256) {
                    int l = rowT * 32 + (e >> 6), mc = c2 * 64 + (e & 63);
                    ws[OFF_A2CAT + b * 81920 + l * 640 + mc] = 0.0f;
                }
            } else {
                float4 c0, c1;
                gemm_tile(ws + OFF_XQ + b * 32768 + rowT * 32 * 256, 256,
                          ws + OFF_X2T + b * 32768 + c2 * 64, 128, 256, smem, c0, c1);
                float cc[2][4] = {{c0.x, c0.y, c0.z, c0.w}, {c1.x, c1.y, c1.z, c1.w}};
#pragma unroll
                for (int i = 0; i < 2; ++i)
#pragma unroll
                    for (int jj = 0; jj < 4; ++jj) {
                        int l = rowT * 32 + 2 * ty + i;
                        int mc = c2 * 64 + 4 * tx + jj;
                        float p = 0.0f;
                        if (mc <= l)
                            p = ws[OFF_A + (b * 128 + l) * 128 + mc] *
                                ws[OFF_LR + b * 128 + mc] * (1.0f + cc[i][jj]);
                        ws[OFF_A2CAT + b * 81920 + l * 640 + mc] = p;
                    }
            }
        }
        __threadfence_block();
        __syncthreads();
        float4 c0, c1;
        gemm_tile(ws + OFF_A2CAT + b * 81920 + rowT * 32 * 640, 640,
                  ws + OFF_B2CAT + b * 163840 + colT * 64, 256, 640, smem, c0, c1);
        float cc[2][4] = {{c0.x, c0.y, c0.z, c0.w}, {c1.x, c1.y, c1.z, c1.w}};
#pragma unroll
        for (int i = 0; i < 2; ++i)
#pragma unroll
            for (int jj = 0; jj < 4; ++jj) {
                int ml = rowT * 32 + 2 * ty + i;
                int n = colT * 64 + 4 * tx + jj;
                float cl = ws[OFF_C + b * 128 + ml];
                float wdv = ws[OFF_WDCUM + b * 128 + ml];
                out[OUT_ZQ2 + (b * 128 + ml) * 256 + n] =
                    cc[i][jj] + wdv * b2[b * 256 + n] - cl * mb2[b * 256 + n];
            }
    }
}

// ---------------------------------------------------------------------------
__global__ __launch_bounds__(256) void init_kernel(unsigned* bar) {
    int t = threadIdx.x;
#pragma unroll
    for (int i = 0; i < 4; ++i)
        bar[t + 256 * i] = 0u;
}

// ---------------------------------------------------------------------------
extern "C" void kernel_launch(void* const* d_in, const int* in_sizes, int n_in,
                              void* d_out, int out_size, void* d_ws, size_t ws_size,
                              hipStream_t stream) {
    const float* x   = (const float*)d_in[0];
    const float* Wq  = (const float*)d_in[1];
    const float* bq  = (const float*)d_in[2];
    const float* Wk  = (const float*)d_in[3];
    const float* bk  = (const float*)d_in[4];
    const float* Wv  = (const float*)d_in[5];
    const float* bv  = (const float*)d_in[6];
    const float* Wlr = (const float*)d_in[7];
    const float* blr = (const float*)d_in[8];
    const float* Wm  = (const float*)d_in[9];
    const float* bm  = (const float*)d_in[10];
    const float* Wd  = (const float*)d_in[11];
    const float* bd  = (const float*)d_in[12];
    const float* W1  = (const float*)d_in[13];
    const float* b1  = (const float*)d_in[14];
    const float* W2  = (const float*)d_in[15];
    const float* b2  = (const float*)d_in[16];
    const float* mW1 = (const float*)d_in[17];
    const float* mb1 = (const float*)d_in[18];
    const float* mW2 = (const float*)d_in[19];
    const float* mb2 = (const float*)d_in[20];
    float* ws  = (float*)d_ws;
    float* out = (float*)d_out;

    init_kernel<<<1, 256, 0, stream>>>((unsigned*)(ws + OFF_BAR));
    fused_kernel<<<NBLK, 256, 0, stream>>>(
        x, Wq, bq, Wk, bk, Wv, bv, Wlr, blr, Wm, bm, Wd, bd,
        W1, b1, W2, b2, mW1, mb1, mW2, mb2, ws, out);
}

// Round 6
// 279.355 us; speedup vs baseline: 1.7724x; 1.0589x over previous
//
#include <hip/hip_runtime.h>
#include <math.h>

// Problem constants
constexpr int Bn = 2, Ln = 128;

// log(expm1(0.01))
#define LR_SHIFT (-4.6001660040607144f)

// ---------------------------------------------------------------------------
// Workspace layout (floats)
// ---------------------------------------------------------------------------
constexpr int OFF_Q      = 0;        // [256 tok][256]
constexpr int OFF_K      = 65536;    // [256 tok][256]
constexpr int OFF_V      = 131072;   // [256 tok][256]
constexpr int OFF_X2     = 196608;   // [256 tok][256]
constexpr int OFF_SILD   = 262144;   // [256 tok][256] silu_backward(Z1)
constexpr int OFF_XQ     = 327680;   // [256 tok][256]
constexpr int OFF_KT     = 393216;   // [B][256 d][128 l]
constexpr int OFF_X2T    = 458752;   // [B][256 h][128 l]
constexpr int OFF_A      = 524288;   // [B][128 l][128 m]  A = Dm@M
constexpr int OFF_B1CAT  = 557056;   // [B][640][256]: rows 0-127 GZ1, 128-383 W1t, 384-639 mW1t
constexpr int OFF_B2CAT  = 884736;   // [B][640][256]: rows 0-127 GZ2, 128-383 W2t, 384-639 mW2t
constexpr int OFF_A1CAT  = 1212416;  // [B][128 l][640]: cols 0-127 P1, 128-383 wd*q, 384-639 -c*q
constexpr int OFF_A2CAT  = 1376256;  // [B][128 l][640]
constexpr int OFF_FC     = 1540096;  // [3][256] raw lr/mom/wd projections
constexpr int OFF_LR     = 1540864;  // [B][128]
constexpr int OFF_PM     = 1541120;  // [B][128]
constexpr int OFF_PD     = 1541376;  // [B][128]
constexpr int OFF_MOMCUM = 1541632;  // [B][128]
constexpr int OFF_WDCUM  = 1541888;  // [B][128]
constexpr int OFF_C      = 1542144;  // [B][128]
constexpr int OFF_BAR    = 1542656;  // 1024 unsigned words barrier region

// Barrier words (unsigned, relative to bar):
//   arrival slots: g*32 + idx   (g = bid&7, idx = bid>>3)    words 0..255
//   rootslot:      320 + g                                    words 320..327
//   grpgen:        448 + g*32                                 words 448..672
// No init needed: 0xAA poison != any epoch (1..5); spins use != epoch.

// Output offsets (floats), tuple order
constexpr int OUT_ZQ2  = 0;
constexpr int OUT_W1P  = 65536;
constexpr int OUT_B1P  = 196608;
constexpr int OUT_W2P  = 197120;
constexpr int OUT_B2P  = 328192;
constexpr int OUT_MGW1 = 328704;
constexpr int OUT_MGB1 = 459776;
constexpr int OUT_MGW2 = 460288;
constexpr int OUT_MGB2 = 591360;

constexpr int NBLK = 256;

__device__ __forceinline__ float softplus_f(float z) {
    return fmaxf(z, 0.0f) + log1pf(expf(-fabsf(z)));
}

__device__ __forceinline__ float dot4(float4 a, float4 b) {
    return a.x * b.x + a.y * b.y + a.z * b.z + a.w * b.w;
}

// ---------------------------------------------------------------------------
// Minimal-fence hierarchical grid barrier.
//  - arrival: ONE release store (waitcnt + buffer_wbl2 + sc1 store)
//  - polls:   RELAXED sc1 loads (no cache maintenance per iteration)
//  - exit:    ONE acquire load (buffer_inv)
// 2 hops: 8 leaders poll own 32 slots -> rootslot; every leader polls all 8
// rootslots -> grpgen; everyone polls its grpgen.
// All 256 blocks co-resident (2 blocks/CU capacity at 12.5KB LDS, 68 VGPR).
// ---------------------------------------------------------------------------
__device__ __forceinline__ void grid_barrier(unsigned* bar, int bid, unsigned epoch) {
    __syncthreads();
    const int t = threadIdx.x;
    const int g = bid & 7, idx = bid >> 3;
    if (t == 0) {
        __hip_atomic_store(&bar[g * 32 + idx], epoch, __ATOMIC_RELEASE,
                           __HIP_MEMORY_SCOPE_AGENT);
    }
    if (bid < 8) {
        if (t < 32) {
            while (__hip_atomic_load(&bar[bid * 32 + t], __ATOMIC_RELAXED,
                                     __HIP_MEMORY_SCOPE_AGENT) != epoch)
                __builtin_amdgcn_s_sleep(2);
        }
        if (t == 0)
            __hip_atomic_store(&bar[320 + bid], epoch, __ATOMIC_RELAXED,
                               __HIP_MEMORY_SCOPE_AGENT);
        if (t < 8) {
            while (__hip_atomic_load(&bar[320 + t], __ATOMIC_RELAXED,
                                     __HIP_MEMORY_SCOPE_AGENT) != epoch)
                __builtin_amdgcn_s_sleep(2);
        }
        if (t == 0)
            __hip_atomic_store(&bar[448 + bid * 32], epoch, __ATOMIC_RELAXED,
                               __HIP_MEMORY_SCOPE_AGENT);
    }
    if (t == 0) {
        while (__hip_atomic_load(&bar[448 + g * 32], __ATOMIC_RELAXED,
                                 __HIP_MEMORY_SCOPE_AGENT) != epoch)
            __builtin_amdgcn_s_sleep(2);
        (void)__hip_atomic_load(&bar[448 + g * 32], __ATOMIC_ACQUIRE,
                                __HIP_MEMORY_SCOPE_AGENT);
    }
    __syncthreads();
}

// ---------------------------------------------------------------------------
// GEMM tile: 32x64 output, 256 threads, 2x4 register tile, KC=32.
// A: [32 rows][K] (lda), B: [K][64 cols] (ldb). smem >= 3136 floats.
// ---------------------------------------------------------------------------
__device__ __forceinline__ void gemm_tile(
    const float* A, int lda, const float* B, int ldb, int K,
    float* smem, float4& c0, float4& c1) {
    float (*As)[34] = (float(*)[34])smem;            // [k][m]
    float (*Bs)[64] = (float(*)[64])(smem + 1088);   // [k][n]
    const int t = threadIdx.x;
    const int tx = t & 15, ty = t >> 4;
    const int am = t >> 3, ak4 = (t & 7) << 2;
    const int bk = t >> 4, bn4 = (t & 15) << 2;
    c0 = make_float4(0.f, 0.f, 0.f, 0.f);
    c1 = make_float4(0.f, 0.f, 0.f, 0.f);
    for (int kc = 0; kc < K; kc += 32) {
        float4 ga  = *(const float4*)(A + am * lda + kc + ak4);
        float4 gb0 = *(const float4*)(B + (kc + bk) * ldb + bn4);
        float4 gb1 = *(const float4*)(B + (kc + bk + 16) * ldb + bn4);
        __syncthreads();
        As[ak4 + 0][am] = ga.x; As[ak4 + 1][am] = ga.y;
        As[ak4 + 2][am] = ga.z; As[ak4 + 3][am] = ga.w;
        *(float4*)&Bs[bk][bn4]      = gb0;
        *(float4*)&Bs[bk + 16][bn4] = gb1;
        __syncthreads();
#pragma unroll
        for (int k = 0; k < 32; ++k) {
            float a0 = As[k][2 * ty], a1 = As[k][2 * ty + 1];
            float4 b4 = *(const float4*)&Bs[k][4 * tx];
            c0.x += a0 * b4.x; c0.y += a0 * b4.y; c0.z += a0 * b4.z; c0.w += a0 * b4.w;
            c1.x += a1 * b4.x; c1.y += a1 * b4.y; c1.z += a1 * b4.z; c1.w += a1 * b4.w;
        }
    }
}

// ---------------------------------------------------------------------------
// lastw job: 32x32 tile of W{1,2}p + mgW{1,2}. K=128.
// ---------------------------------------------------------------------------
__device__ __forceinline__ void lastw_job(
    int b, int fam, int i0, int j0,
    const float* W1, const float* mW1, const float* W2, const float* mW2,
    float* ws, float* out, float* smem) {
    const int t = threadIdx.x;
    float* wa = smem;
    float* wm = smem + 128;
    float (*Ls)[36] = (float(*)[36])(smem + 256);
    float (*Rs)[36] = (float(*)[36])(smem + 256 + 1152);
    __syncthreads();
    if (t < 128) {
        float lrv = ws[OFF_LR + b * 128 + t];
        wa[t] = ws[OFF_A + (b * 128 + 127) * 128 + t] * lrv;
        wm[t] = expf(ws[OFF_PM + b * 128 + 127] - ws[OFF_PM + b * 128 + t]) * lrv;
    }
    const float* left  = ws + (fam ? OFF_B2CAT : OFF_B1CAT) + b * 163840;
    const float* right = ws + (fam ? OFF_X2 : OFF_K) + b * 32768;
    float accA[2][2] = {{0.f, 0.f}, {0.f, 0.f}};
    float accM[2][2] = {{0.f, 0.f}, {0.f, 0.f}};
    int tx = t & 15, ty = t >> 4;
    int lrow = t >> 3, lc4 = (t & 7) << 2;
    for (int kc = 0; kc < 128; kc += 32) {
        __syncthreads();
        *(float4*)&Ls[lrow][lc4] = *(const float4*)(left + (kc + lrow) * 256 + i0 + lc4);
        *(float4*)&Rs[lrow][lc4] = *(const float4*)(right + (kc + lrow) * 256 + j0 + lc4);
        __syncthreads();
#pragma unroll
        for (int k = 0; k < 32; ++k) {
            float wak = wa[kc + k], wmk = wm[kc + k];
            float l0 = Ls[k][2 * ty], l1 = Ls[k][2 * ty + 1];
            float r0 = Rs[k][2 * tx], r1 = Rs[k][2 * tx + 1];
            float p00 = l0 * r0, p01 = l0 * r1, p10 = l1 * r0, p11 = l1 * r1;
            accA[0][0] += wak * p00; accA[0][1] += wak * p01;
            accA[1][0] += wak * p10; accA[1][1] += wak * p11;
            accM[0][0] += wmk * p00; accM[0][1] += wmk * p01;
            accM[1][0] += wmk * p10; accM[1][1] += wmk * p11;
        }
    }
    float c_last  = ws[OFF_C + b * 128 + 127];
    float wd_last = ws[OFF_WDCUM + b * 128 + 127];
    float mc_last = ws[OFF_MOMCUM + b * 128 + 127];
    const float* base1 = (fam ? W2 : W1) + b * 65536;
    const float* basem = (fam ? mW2 : mW1) + b * 65536;
    int opB = fam ? OUT_W2P : OUT_W1P;
    int omB = fam ? OUT_MGW2 : OUT_MGW1;
#pragma unroll
    for (int di = 0; di < 2; ++di)
#pragma unroll
        for (int dj = 0; dj < 2; ++dj) {
            int i = i0 + 2 * ty + di, j = j0 + 2 * tx + dj;
            float b1v = base1[i * 256 + j], bmv = basem[i * 256 + j];
            out[opB + (b * 256 + i) * 256 + j] = accA[di][dj] - c_last * bmv + wd_last * b1v;
            out[omB + (b * 256 + i) * 256 + j] = accM[di][dj] - mc_last * bmv;
        }
}

// ---------------------------------------------------------------------------
// The fused kernel: 256 blocks x 256 threads, 6 stages, 5 grid barriers.
// ---------------------------------------------------------------------------
__global__ __launch_bounds__(256) void fused_kernel(
    const float* x,
    const float* Wq, const float* bq,
    const float* Wk, const float* bk,
    const float* Wv, const float* bv,
    const float* Wlr, const float* blr,
    const float* Wm, const float* bm,
    const float* Wd, const float* bd,
    const float* W1, const float* b1,
    const float* W2, const float* b2,
    const float* mW1, const float* mb1,
    const float* mW2, const float* mb2,
    float* ws, float* out) {
    __shared__ float smem[3136];
    const int bid = blockIdx.x;
    const int t = threadIdx.x;
    const int tx = t & 15, ty = t >> 4;
    unsigned* bar = (unsigned*)(ws + OFF_BAR);

    // ======== S0: qkv GEMMs (96 blocks) + scalars (8) + transposes (152) ====
    if (bid < 96) {
        int which = bid / 32, tile = bid % 32, rowT = tile >> 2, colT = tile & 3;
        const float* Wp = which == 0 ? Wq : (which == 1 ? Wk : Wv);
        const float* bp = which == 0 ? bq : (which == 1 ? bk : bv);
        float4 c0, c1;
        gemm_tile(x + rowT * 32 * 256, 256, Wp + colT * 64, 256, 256, smem, c0, c1);
        float cc[2][4] = {{c0.x, c0.y, c0.z, c0.w}, {c1.x, c1.y, c1.z, c1.w}};
#pragma unroll
        for (int i = 0; i < 2; ++i)
#pragma unroll
            for (int jj = 0; jj < 4; ++jj) {
                int m = rowT * 32 + 2 * ty + i;
                int c = colT * 64 + 4 * tx + jj;
                float v = cc[i][jj] + bp[c];
                if (which == 0) {
                    ws[OFF_Q + m * 256 + c] = v;
                } else if (which == 1) {
                    ws[OFF_K + m * 256 + c] = v;
                    ws[OFF_KT + (m >> 7) * 32768 + c * 128 + (m & 127)] = v;
                } else {
                    ws[OFF_V + m * 256 + c] = v;
                }
            }
    } else if (bid < 104) {
        // scalar projections for 32 tokens: wave w handles 8 tokens
        int tk0 = (bid - 96) * 32;
        float* ww = smem;
        ww[t] = Wlr[t]; ww[256 + t] = Wm[t]; ww[512 + t] = Wd[t];
        __syncthreads();
        int wv = t >> 6, lane = t & 63;
        float4 wl = *(const float4*)(ww + lane * 4);
        float4 wmv = *(const float4*)(ww + 256 + lane * 4);
        float4 wdv = *(const float4*)(ww + 512 + lane * 4);
        for (int i = 0; i < 8; ++i) {
            int tok = tk0 + wv * 8 + i;
            float4 xv = *(const float4*)(x + tok * 256 + lane * 4);
            float d0 = dot4(xv, wl), d1 = dot4(xv, wmv), d2 = dot4(xv, wdv);
#pragma unroll
            for (int off = 32; off > 0; off >>= 1) {
                d0 += __shfl_down(d0, off);
                d1 += __shfl_down(d1, off);
                d2 += __shfl_down(d2, off);
            }
            if (lane == 0) {
                ws[OFF_FC + tok] = d0;
                ws[OFF_FC + 256 + tok] = d1;
                ws[OFF_FC + 512 + tok] = d2;
            }
        }
    } else {
        // transpose W1/W2/mW1/mW2 32x32 tiles into CAT slots (512 jobs)
        for (int j2 = bid - 104; j2 < 512; j2 += 152) {
            __syncthreads();
            int mat = j2 >> 7, rem = j2 & 127, b = rem >> 6, tile = rem & 63;
            int r0 = (tile >> 3) * 32, c0 = (tile & 7) * 32;
            const float* src; float* dst;
            if (mat == 0)      { src = W1  + b * 65536; dst = ws + OFF_B1CAT + b * 163840 + 128 * 256; }
            else if (mat == 1) { src = W2  + b * 65536; dst = ws + OFF_B2CAT + b * 163840 + 128 * 256; }
            else if (mat == 2) { src = mW1 + b * 65536; dst = ws + OFF_B1CAT + b * 163840 + 384 * 256; }
            else               { src = mW2 + b * 65536; dst = ws + OFF_B2CAT + b * 163840 + 384 * 256; }
            float (*tl)[33] = (float(*)[33])smem;
            int ttx = t & 31, tty = t >> 5;
#pragma unroll
            for (int i = 0; i < 32; i += 8)
                tl[tty + i][ttx] = src[(r0 + tty + i) * 256 + (c0 + ttx)];
            __syncthreads();
#pragma unroll
            for (int i = 0; i < 32; i += 8)
                dst[(c0 + tty + i) * 256 + (r0 + ttx)] = tl[ttx][tty + i];
        }
    }
    grid_barrier(bar, bid, 1u);

    // ======== S1: z1 GEMM -> X2/X2T/SILD; block 32 does the scans ========
    if (bid < 32) {
        int b = bid >> 4, tile = bid & 15, rowT = tile >> 2, colT = tile & 3;
        float4 c0, c1;
        gemm_tile(ws + OFF_K + b * 32768 + rowT * 32 * 256, 256,
                  ws + OFF_B1CAT + b * 163840 + 128 * 256 + colT * 64, 256, 256,
                  smem, c0, c1);
        float cc[2][4] = {{c0.x, c0.y, c0.z, c0.w}, {c1.x, c1.y, c1.z, c1.w}};
#pragma unroll
        for (int i = 0; i < 2; ++i)
#pragma unroll
            for (int jj = 0; jj < 4; ++jj) {
                int ml = rowT * 32 + 2 * ty + i;
                int n = colT * 64 + 4 * tx + jj;
                float z = cc[i][jj] + b1[b * 256 + n];
                float sg = 1.0f / (1.0f + expf(-z));
                float x2 = z * sg;
                int gm = b * 128 + ml;
                ws[OFF_X2 + gm * 256 + n] = x2;
                ws[OFF_X2T + b * 32768 + n * 128 + ml] = x2;
                ws[OFF_SILD + gm * 256 + n] = x2 + sg * (1.0f - x2);
            }
    } else if (bid == 32) {
        // both batches' scans (t = b*128 + i)
        int i = t & 127;
        float* sm = smem; float* sd = smem + 256; float* se = smem + 512;
        ws[OFF_LR + t] = softplus_f(ws[OFF_FC + t] + blr[0] + LR_SHIFT);
        float lm = -softplus_f(-(ws[OFF_FC + 256 + t] + bm[0]));
        float ld = -softplus_f(ws[OFF_FC + 512 + t] + bd[0]);
        sm[t] = lm; sd[t] = ld;
        __syncthreads();
        for (int off = 1; off < 128; off <<= 1) {
            float am_ = (i >= off) ? sm[t - off] : 0.0f;
            float ad_ = (i >= off) ? sd[t - off] : 0.0f;
            __syncthreads();
            sm[t] += am_; sd[t] += ad_;
            __syncthreads();
        }
        float pm = sm[t], pd = sd[t];
        ws[OFF_PM + t] = pm;
        ws[OFF_PD + t] = pd;
        ws[OFF_MOMCUM + t] = expf(pm);
        ws[OFF_WDCUM + t] = expf(pd);
        se[t] = expf(pm - pd);
        __syncthreads();
        for (int off = 1; off < 128; off <<= 1) {
            float a_ = (i >= off) ? se[t - off] : 0.0f;
            __syncthreads();
            se[t] += a_;
            __syncthreads();
        }
        ws[OFF_C + t] = expf(pd) * se[t];
    }
    grid_barrier(bar, bid, 2u);

    // ======== S2: z2 GEMM -> GZ2; decay-matrix A + A1CAT q-slots ========
    for (int j = bid; j < 288; j += NBLK) {
        __syncthreads();
        if (j < 32) {
            int b = j >> 4, tile = j & 15, rowT = tile >> 2, colT = tile & 3;
            float4 c0, c1;
            gemm_tile(ws + OFF_X2 + b * 32768 + rowT * 32 * 256, 256,
                      ws + OFF_B2CAT + b * 163840 + 128 * 256 + colT * 64, 256, 256,
                      smem, c0, c1);
            float cc[2][4] = {{c0.x, c0.y, c0.z, c0.w}, {c1.x, c1.y, c1.z, c1.w}};
#pragma unroll
            for (int i = 0; i < 2; ++i)
#pragma unroll
                for (int jj = 0; jj < 4; ++jj) {
                    int ml = rowT * 32 + 2 * ty + i;
                    int n = colT * 64 + 4 * tx + jj;
                    int gm = b * 128 + ml;
                    float gz2 = cc[i][jj] + b2[b * 256 + n] - ws[OFF_V + gm * 256 + n];
                    ws[OFF_B2CAT + b * 163840 + ml * 256 + n] = gz2;
                }
        } else {
            int bl = j - 32, b = bl >> 7, l = bl & 127;
            if (t < 128) {
                float a = 0.0f;
                if (t <= l) {
                    const float* Pm = ws + OFF_PM + b * 128;
                    const float* Pd = ws + OFF_PD + b * 128;
                    float pdl = Pd[l], pmm = Pm[t], s = 0.0f;
                    for (int mm = t; mm <= l; ++mm)
                        s += expf((pdl - Pd[mm]) + (Pm[mm] - pmm));
                    a = s;
                }
                ws[OFF_A + bl * 128 + t] = a;
            }
            float q  = ws[OFF_Q + bl * 256 + t];
            float wdv = ws[OFF_WDCUM + b * 128 + l];
            float cl = ws[OFF_C + b * 128 + l];
            float* A1 = ws + OFF_A1CAT + b * 81920 + l * 640;
            A1[128 + t] = wdv * q;
            A1[384 + t] = -cl * q;
        }
    }
    grid_barrier(bar, bid, 3u);

    // ======== S3: gx2 GEMM -> GZ1; lastw fam=1 (W2p/mgW2) ========
    if (bid < 32) {
        int b = bid >> 4, tile = bid & 15, rowT = tile >> 2, colT = tile & 3;
        float4 c0, c1;
        gemm_tile(ws + OFF_B2CAT + b * 163840 + rowT * 32 * 256, 256,
                  W2 + b * 65536 + colT * 64, 256, 256, smem, c0, c1);
        float cc[2][4] = {{c0.x, c0.y, c0.z, c0.w}, {c1.x, c1.y, c1.z, c1.w}};
#pragma unroll
        for (int i = 0; i < 2; ++i)
#pragma unroll
            for (int jj = 0; jj < 4; ++jj) {
                int ml = rowT * 32 + 2 * ty + i;
                int n = colT * 64 + 4 * tx + jj;
                int gm = b * 128 + ml;
                float gz1 = cc[i][jj] * ws[OFF_SILD + gm * 256 + n];
                ws[OFF_B1CAT + b * 163840 + ml * 256 + n] = gz1;
            }
    } else if (bid < 160) {
        int jdx = bid - 32, b = jdx >> 6, tile = jdx & 63;
        lastw_job(b, 1, (tile >> 3) * 32, (tile & 7) * 32,
                  W1, mW1, W2, mW2, ws, out, smem);
    }
    grid_barrier(bar, bid, 4u);

    // ======== S4: zq1 (score1 inline, K=640); lastw fam=0; lastb ========
    if (bid < 32) {
        int b = bid >> 4, tile = bid & 15, rowT = tile >> 2, colT = tile & 3;
        // score part: this block computes P1 rows [rowT*32,+32), cols 0..127
        // (the 4 colT blocks per rowT produce bit-identical copies; benign)
        for (int c2 = 0; c2 < 2; ++c2) {
            __syncthreads();
            if (c2 * 64 > rowT * 32 + 31) {
                for (int e = t; e < 2048; e += 256) {
                    int l = rowT * 32 + (e >> 6), mc = c2 * 64 + (e & 63);
                    ws[OFF_A1CAT + b * 81920 + l * 640 + mc] = 0.0f;
                }
            } else {
                float4 c0, c1;
                gemm_tile(ws + OFF_Q + b * 32768 + rowT * 32 * 256, 256,
                          ws + OFF_KT + b * 32768 + c2 * 64, 128, 256, smem, c0, c1);
                float cc[2][4] = {{c0.x, c0.y, c0.z, c0.w}, {c1.x, c1.y, c1.z, c1.w}};
#pragma unroll
                for (int i = 0; i < 2; ++i)
#pragma unroll
                    for (int jj = 0; jj < 4; ++jj) {
                        int l = rowT * 32 + 2 * ty + i;
                        int mc = c2 * 64 + 4 * tx + jj;
                        float p = 0.0f;
                        if (mc <= l)
                            p = ws[OFF_A + (b * 128 + l) * 128 + mc] *
                                ws[OFF_LR + b * 128 + mc] * (1.0f + cc[i][jj]);
                        ws[OFF_A1CAT + b * 81920 + l * 640 + mc] = p;
                    }
            }
        }
        __syncthreads();
        float4 c0, c1;
        gemm_tile(ws + OFF_A1CAT + b * 81920 + rowT * 32 * 640, 640,
                  ws + OFF_B1CAT + b * 163840 + colT * 64, 256, 640, smem, c0, c1);
        float cc[2][4] = {{c0.x, c0.y, c0.z, c0.w}, {c1.x, c1.y, c1.z, c1.w}};
#pragma unroll
        for (int i = 0; i < 2; ++i)
#pragma unroll
            for (int jj = 0; jj < 4; ++jj) {
                int ml = rowT * 32 + 2 * ty + i;
                int n = colT * 64 + 4 * tx + jj;
                float cl = ws[OFF_C + b * 128 + ml];
                float wdv = ws[OFF_WDCUM + b * 128 + ml];
                float z = cc[i][jj] + wdv * b1[b * 256 + n] - cl * mb1[b * 256 + n];
                float sg = 1.0f / (1.0f + expf(-z));
                float xq = z * sg;
                ws[OFF_XQ + (b * 128 + ml) * 256 + n] = xq;
                float* A2 = ws + OFF_A2CAT + b * 81920 + ml * 640;
                A2[128 + n] = wdv * xq;
                A2[384 + n] = -cl * xq;
            }
    } else if (bid < 160) {
        int jdx = bid - 32, b = jdx >> 6, tile = jdx & 63;
        lastw_job(b, 0, (tile >> 3) * 32, (tile & 7) * 32,
                  W1, mW1, W2, mW2, ws, out, smem);
    } else if (bid < 162) {
        int b = bid - 160;
        float* wa = smem; float* wm = smem + 128;
        if (t < 128) {
            float lrv = ws[OFF_LR + b * 128 + t];
            wa[t] = ws[OFF_A + (b * 128 + 127) * 128 + t] * lrv;
            wm[t] = expf(ws[OFF_PM + b * 128 + 127] - ws[OFF_PM + b * 128 + t]) * lrv;
        }
        __syncthreads();
        const float* gz1 = ws + OFF_B1CAT + b * 163840;
        const float* gz2 = ws + OFF_B2CAT + b * 163840;
        float sA1 = 0, sM1 = 0, sA2 = 0, sM2 = 0;
#pragma unroll 4
        for (int m = 0; m < 128; ++m) {
            float g1 = gz1[m * 256 + t], g2 = gz2[m * 256 + t];
            sA1 += wa[m] * g1; sM1 += wm[m] * g1;
            sA2 += wa[m] * g2; sM2 += wm[m] * g2;
        }
        float c_last  = ws[OFF_C + b * 128 + 127];
        float wd_last = ws[OFF_WDCUM + b * 128 + 127];
        float mc_last = ws[OFF_MOMCUM + b * 128 + 127];
        out[OUT_B1P + b * 256 + t]  = sA1 - c_last * mb1[b * 256 + t] + wd_last * b1[b * 256 + t];
        out[OUT_MGB1 + b * 256 + t] = sM1 - mc_last * mb1[b * 256 + t];
        out[OUT_B2P + b * 256 + t]  = sA2 - c_last * mb2[b * 256 + t] + wd_last * b2[b * 256 + t];
        out[OUT_MGB2 + b * 256 + t] = sM2 - mc_last * mb2[b * 256 + t];
    }
    grid_barrier(bar, bid, 5u);

    // ======== S5: zq2 (score2 inline, K=640) -> out ========
    if (bid < 32) {
        int b = bid >> 4, tile = bid & 15, rowT = tile >> 2, colT = tile & 3;
        for (int c2 = 0; c2 < 2; ++c2) {
            __syncthreads();
            if (c2 * 64 > rowT * 32 + 31) {
                for (int e = t; e < 2048; e += 256) {
                    int l = rowT * 32 + (e >> 6), mc = c2 * 64 + (e & 63);
                    ws[OFF_A2CAT + b * 81920 + l * 640 + mc] = 0.0f;
                }
            } else {
                float4 c0, c1;
                gemm_tile(ws + OFF_XQ + b * 32768 + rowT * 32 * 256, 256,
                          ws + OFF_X2T + b * 32768 + c2 * 64, 128, 256, smem, c0, c1);
                float cc[2][4] = {{c0.x, c0.y, c0.z, c0.w}, {c1.x, c1.y, c1.z, c1.w}};
#pragma unroll
                for (int i = 0; i < 2; ++i)
#pragma unroll
                    for (int jj = 0; jj < 4; ++jj) {
                        int l = rowT * 32 + 2 * ty + i;
                        int mc = c2 * 64 + 4 * tx + jj;
                        float p = 0.0f;
                        if (mc <= l)
                            p = ws[OFF_A + (b * 128 + l) * 128 + mc] *
                                ws[OFF_LR + b * 128 + mc] * (1.0f + cc[i][jj]);
                        ws[OFF_A2CAT + b * 81920 + l * 640 + mc] = p;
                    }
            }
        }
        __syncthreads();
        float4 c0, c1;
        gemm_tile(ws + OFF_A2CAT + b * 81920 + rowT * 32 * 640, 640,
                  ws + OFF_B2CAT + b * 163840 + colT * 64, 256, 640, smem, c0, c1);
        float cc[2][4] = {{c0.x, c0.y, c0.z, c0.w}, {c1.x, c1.y, c1.z, c1.w}};
#pragma unroll
        for (int i = 0; i < 2; ++i)
#pragma unroll
            for (int jj = 0; jj < 4; ++jj) {
                int ml = rowT * 32 + 2 * ty + i;
                int n = colT * 64 + 4 * tx + jj;
                float cl = ws[OFF_C + b * 128 + ml];
                float wdv = ws[OFF_WDCUM + b * 128 + ml];
                out[OUT_ZQ2 + (b * 128 + ml) * 256 + n] =
                    cc[i][jj] + wdv * b2[b * 256 + n] - cl * mb2[b * 256 + n];
            }
    }
}

// ---------------------------------------------------------------------------
extern "C" void kernel_launch(void* const* d_in, const int* in_sizes, int n_in,
                              void* d_out, int out_size, void* d_ws, size_t ws_size,
                              hipStream_t stream) {
    const float* x   = (const float*)d_in[0];
    const float* Wq  = (const float*)d_in[1];
    const float* bq  = (const float*)d_in[2];
    const float* Wk  = (const float*)d_in[3];
    const float* bk  = (const float*)d_in[4];
    const float* Wv  = (const float*)d_in[5];
    const float* bv  = (const float*)d_in[6];
    const float* Wlr = (const float*)d_in[7];
    const float* blr = (const float*)d_in[8];
    const float* Wm  = (const float*)d_in[9];
    const float* bm  = (const float*)d_in[10];
    const float* Wd  = (const float*)d_in[11];
    const float* bd  = (const float*)d_in[12];
    const float* W1  = (const float*)d_in[13];
    const float* b1  = (const float*)d_in[14];
    const float* W2  = (const float*)d_in[15];
    const float* b2  = (const float*)d_in[16];
    const float* mW1 = (const float*)d_in[17];
    const float* mb1 = (const float*)d_in[18];
    const float* mW2 = (const float*)d_in[19];
    const float* mb2 = (const float*)d_in[20];
    float* ws  = (float*)d_ws;
    float* out = (float*)d_out;

    fused_kernel<<<NBLK, 256, 0, stream>>>(
        x, Wq, bq, Wk, bk, Wv, bv, Wlr, blr, Wm, bm, Wd, bd,
        W1, b1, W2, b2, mW1, mb1, mW2, mb2, ws, out);
}

// Round 7
// 256.592 us; speedup vs baseline: 1.9296x; 1.0887x over previous
//
#include <hip/hip_runtime.h>
#include <math.h>

// Problem constants
constexpr int Bn = 2, Ln = 128;

// log(expm1(0.01))
#define LR_SHIFT (-4.6001660040607144f)

// ---------------------------------------------------------------------------
// Workspace layout (floats)
// ---------------------------------------------------------------------------
constexpr int OFF_Q      = 0;        // [256 tok][256]
constexpr int OFF_K      = 65536;    // [256 tok][256]
constexpr int OFF_V      = 131072;   // [256 tok][256]
constexpr int OFF_X2     = 196608;   // [256 tok][256]
constexpr int OFF_SILD   = 262144;   // [256 tok][256] silu_backward(Z1)
constexpr int OFF_XQ     = 327680;   // [256 tok][256]
constexpr int OFF_KT     = 393216;   // [B][256 d][128 l]
constexpr int OFF_X2T    = 458752;   // [B][256 h][128 l]
constexpr int OFF_A      = 524288;   // [B][128 l][128 m]  A = Dm@M
constexpr int OFF_B1CAT  = 557056;   // [B][640][256]: rows 0-127 GZ1, 128-383 W1t, 384-639 mW1t
constexpr int OFF_B2CAT  = 884736;   // [B][640][256]: rows 0-127 GZ2, 128-383 W2t, 384-639 mW2t
constexpr int OFF_A1CAT  = 1212416;  // [B][128 l][640]: cols 0-127 P1, 128-383 wd*q, 384-639 -c*q
constexpr int OFF_A2CAT  = 1376256;  // [B][128 l][640]
constexpr int OFF_FC     = 1540096;  // [3][256] raw lr/mom/wd projections
constexpr int OFF_LR     = 1540864;  // [B][128]
constexpr int OFF_PM     = 1541120;  // [B][128]
constexpr int OFF_PD     = 1541376;  // [B][128]
constexpr int OFF_MOMCUM = 1541632;  // [B][128]
constexpr int OFF_WDCUM  = 1541888;  // [B][128]
constexpr int OFF_C      = 1542144;  // [B][128]
constexpr int OFF_BAR    = 1542656;  // 1024 unsigned words barrier region

// Barrier words (unsigned, relative to bar):
//   arrival slots: g*32 + idx   (g = bid&7, idx = bid>>3)    words 0..255
//   rootslot:      320 + g                                    words 320..327
//   grpgen:        448 + g*32                                 words 448..672
// No init needed: 0xAA poison != any epoch (1..5); spins use != epoch;
// all flag ops are atomic RMWs -> always performed at the coherence point.

// Output offsets (floats), tuple order
constexpr int OUT_ZQ2  = 0;
constexpr int OUT_W1P  = 65536;
constexpr int OUT_B1P  = 196608;
constexpr int OUT_W2P  = 197120;
constexpr int OUT_B2P  = 328192;
constexpr int OUT_MGW1 = 328704;
constexpr int OUT_MGB1 = 459776;
constexpr int OUT_MGW2 = 460288;
constexpr int OUT_MGB2 = 591360;

constexpr int NBLK = 256;

__device__ __forceinline__ float softplus_f(float z) {
    return fmaxf(z, 0.0f) + log1pf(expf(-fabsf(z)));
}

__device__ __forceinline__ float dot4(float4 a, float4 b) {
    return a.x * b.x + a.y * b.y + a.z * b.z + a.w * b.w;
}

// ---------------------------------------------------------------------------
// RMW-poll hierarchical grid barrier.
// Plain RELAXED loads may be served from a stale (non-snooped) per-XCD L2;
// atomic RMWs always execute at the coherence point. So:
//  - every flag WRITE is an atomic_exchange (arrival one is RELEASE -> 1 wbl2)
//  - every flag POLL is fetch_add(p, 0) RELAXED (fresh, no cache maintenance)
//  - exit does ONE ACQUIRE fetch_add(0) -> 1 buffer_inv for data visibility.
// All 256 blocks co-resident (>=2 blocks/CU capacity at 12.5KB LDS).
// ---------------------------------------------------------------------------
__device__ __forceinline__ unsigned rmw_read(unsigned* p) {
    return __hip_atomic_fetch_add(p, 0u, __ATOMIC_RELAXED, __HIP_MEMORY_SCOPE_AGENT);
}

__device__ __forceinline__ void grid_barrier(unsigned* bar, int bid, unsigned epoch) {
    __syncthreads();
    const int t = threadIdx.x;
    const int g = bid & 7;
    if (t == 0) {
        __hip_atomic_exchange(&bar[(bid & 7) * 32 + (bid >> 3)], epoch,
                              __ATOMIC_RELEASE, __HIP_MEMORY_SCOPE_AGENT);
    }
    if (bid < 8) {
        if (t < 32) {
            while (rmw_read(&bar[bid * 32 + t]) != epoch)
                __builtin_amdgcn_s_sleep(1);
        }
        if (t == 0)
            __hip_atomic_exchange(&bar[320 + bid], epoch, __ATOMIC_RELAXED,
                                  __HIP_MEMORY_SCOPE_AGENT);
        if (t < 8) {
            while (rmw_read(&bar[320 + t]) != epoch)
                __builtin_amdgcn_s_sleep(1);
        }
        if (t == 0)
            __hip_atomic_exchange(&bar[448 + bid * 32], epoch, __ATOMIC_RELAXED,
                                  __HIP_MEMORY_SCOPE_AGENT);
    }
    if (t == 0) {
        while (rmw_read(&bar[448 + g * 32]) != epoch)
            __builtin_amdgcn_s_sleep(1);
        (void)__hip_atomic_fetch_add(&bar[448 + g * 32], 0u, __ATOMIC_ACQUIRE,
                                     __HIP_MEMORY_SCOPE_AGENT);
    }
    __syncthreads();
}

// ---------------------------------------------------------------------------
// GEMM tile: 32x64 output, 256 threads, 2x4 register tile, KC=32.
// Double-buffered: chunk k+1's global loads are issued before chunk k's
// compute, hiding the ~800-cycle MALL latency behind the 640-cycle MAC loop.
// A: [32 rows][K] (lda), B: [K][64 cols] (ldb). smem >= 3136 floats.
// ---------------------------------------------------------------------------
__device__ __forceinline__ void gemm_tile(
    const float* A, int lda, const float* B, int ldb, int K,
    float* smem, float4& c0, float4& c1) {
    float (*As)[34] = (float(*)[34])smem;            // [k][m]
    float (*Bs)[64] = (float(*)[64])(smem + 1088);   // [k][n]
    const int t = threadIdx.x;
    const int tx = t & 15, ty = t >> 4;
    const int am = t >> 3, ak4 = (t & 7) << 2;
    const int bk = t >> 4, bn4 = (t & 15) << 2;
    c0 = make_float4(0.f, 0.f, 0.f, 0.f);
    c1 = make_float4(0.f, 0.f, 0.f, 0.f);
    float4 ga  = *(const float4*)(A + am * lda + ak4);
    float4 gb0 = *(const float4*)(B + bk * ldb + bn4);
    float4 gb1 = *(const float4*)(B + (bk + 16) * ldb + bn4);
    for (int kc = 0; kc < K; kc += 32) {
        __syncthreads();   // previous chunk's LDS reads done
        As[ak4 + 0][am] = ga.x; As[ak4 + 1][am] = ga.y;
        As[ak4 + 2][am] = ga.z; As[ak4 + 3][am] = ga.w;
        *(float4*)&Bs[bk][bn4]      = gb0;
        *(float4*)&Bs[bk + 16][bn4] = gb1;
        __syncthreads();
        if (kc + 32 < K) {  // prefetch next chunk while computing this one
            ga  = *(const float4*)(A + am * lda + kc + 32 + ak4);
            gb0 = *(const float4*)(B + (kc + 32 + bk) * ldb + bn4);
            gb1 = *(const float4*)(B + (kc + 32 + bk + 16) * ldb + bn4);
        }
#pragma unroll
        for (int k = 0; k < 32; ++k) {
            float a0 = As[k][2 * ty], a1 = As[k][2 * ty + 1];
            float4 b4 = *(const float4*)&Bs[k][4 * tx];
            c0.x += a0 * b4.x; c0.y += a0 * b4.y; c0.z += a0 * b4.z; c0.w += a0 * b4.w;
            c1.x += a1 * b4.x; c1.y += a1 * b4.y; c1.z += a1 * b4.z; c1.w += a1 * b4.w;
        }
    }
}

// ---------------------------------------------------------------------------
// lastw job: 32x32 tile of W{1,2}p + mgW{1,2}. K=128, double-buffered.
// ---------------------------------------------------------------------------
__device__ __forceinline__ void lastw_job(
    int b, int fam, int i0, int j0,
    const float* W1, const float* mW1, const float* W2, const float* mW2,
    float* ws, float* out, float* smem) {
    const int t = threadIdx.x;
    float* wa = smem;
    float* wm = smem + 128;
    float (*Ls)[36] = (float(*)[36])(smem + 256);
    float (*Rs)[36] = (float(*)[36])(smem + 256 + 1152);
    __syncthreads();
    if (t < 128) {
        float lrv = ws[OFF_LR + b * 128 + t];
        wa[t] = ws[OFF_A + (b * 128 + 127) * 128 + t] * lrv;
        wm[t] = expf(ws[OFF_PM + b * 128 + 127] - ws[OFF_PM + b * 128 + t]) * lrv;
    }
    const float* left  = ws + (fam ? OFF_B2CAT : OFF_B1CAT) + b * 163840;
    const float* right = ws + (fam ? OFF_X2 : OFF_K) + b * 32768;
    float accA[2][2] = {{0.f, 0.f}, {0.f, 0.f}};
    float accM[2][2] = {{0.f, 0.f}, {0.f, 0.f}};
    int tx = t & 15, ty = t >> 4;
    int lrow = t >> 3, lc4 = (t & 7) << 2;
    float4 gl = *(const float4*)(left + lrow * 256 + i0 + lc4);
    float4 gr = *(const float4*)(right + lrow * 256 + j0 + lc4);
    for (int kc = 0; kc < 128; kc += 32) {
        __syncthreads();
        *(float4*)&Ls[lrow][lc4] = gl;
        *(float4*)&Rs[lrow][lc4] = gr;
        __syncthreads();
        if (kc + 32 < 128) {
            gl = *(const float4*)(left + (kc + 32 + lrow) * 256 + i0 + lc4);
            gr = *(const float4*)(right + (kc + 32 + lrow) * 256 + j0 + lc4);
        }
#pragma unroll
        for (int k = 0; k < 32; ++k) {
            float wak = wa[kc + k], wmk = wm[kc + k];
            float l0 = Ls[k][2 * ty], l1 = Ls[k][2 * ty + 1];
            float r0 = Rs[k][2 * tx], r1 = Rs[k][2 * tx + 1];
            float p00 = l0 * r0, p01 = l0 * r1, p10 = l1 * r0, p11 = l1 * r1;
            accA[0][0] += wak * p00; accA[0][1] += wak * p01;
            accA[1][0] += wak * p10; accA[1][1] += wak * p11;
            accM[0][0] += wmk * p00; accM[0][1] += wmk * p01;
            accM[1][0] += wmk * p10; accM[1][1] += wmk * p11;
        }
    }
    float c_last  = ws[OFF_C + b * 128 + 127];
    float wd_last = ws[OFF_WDCUM + b * 128 + 127];
    float mc_last = ws[OFF_MOMCUM + b * 128 + 127];
    const float* base1 = (fam ? W2 : W1) + b * 65536;
    const float* basem = (fam ? mW2 : mW1) + b * 65536;
    int opB = fam ? OUT_W2P : OUT_W1P;
    int omB = fam ? OUT_MGW2 : OUT_MGW1;
#pragma unroll
    for (int di = 0; di < 2; ++di)
#pragma unroll
        for (int dj = 0; dj < 2; ++dj) {
            int i = i0 + 2 * ty + di, j = j0 + 2 * tx + dj;
            float b1v = base1[i * 256 + j], bmv = basem[i * 256 + j];
            out[opB + (b * 256 + i) * 256 + j] = accA[di][dj] - c_last * bmv + wd_last * b1v;
            out[omB + (b * 256 + i) * 256 + j] = accM[di][dj] - mc_last * bmv;
        }
}

// ---------------------------------------------------------------------------
// The fused kernel: 256 blocks x 256 threads, 6 stages, 5 grid barriers.
// ---------------------------------------------------------------------------
__global__ __launch_bounds__(256) void fused_kernel(
    const float* x,
    const float* Wq, const float* bq,
    const float* Wk, const float* bk,
    const float* Wv, const float* bv,
    const float* Wlr, const float* blr,
    const float* Wm, const float* bm,
    const float* Wd, const float* bd,
    const float* W1, const float* b1,
    const float* W2, const float* b2,
    const float* mW1, const float* mb1,
    const float* mW2, const float* mb2,
    float* ws, float* out) {
    __shared__ float smem[3136];
    const int bid = blockIdx.x;
    const int t = threadIdx.x;
    const int tx = t & 15, ty = t >> 4;
    unsigned* bar = (unsigned*)(ws + OFF_BAR);

    // ======== S0: qkv GEMMs (96 blocks) + scalars (8) + transposes (152) ====
    if (bid < 96) {
        int which = bid / 32, tile = bid % 32, rowT = tile >> 2, colT = tile & 3;
        const float* Wp = which == 0 ? Wq : (which == 1 ? Wk : Wv);
        const float* bp = which == 0 ? bq : (which == 1 ? bk : bv);
        float4 c0, c1;
        gemm_tile(x + rowT * 32 * 256, 256, Wp + colT * 64, 256, 256, smem, c0, c1);
        float cc[2][4] = {{c0.x, c0.y, c0.z, c0.w}, {c1.x, c1.y, c1.z, c1.w}};
#pragma unroll
        for (int i = 0; i < 2; ++i)
#pragma unroll
            for (int jj = 0; jj < 4; ++jj) {
                int m = rowT * 32 + 2 * ty + i;
                int c = colT * 64 + 4 * tx + jj;
                float v = cc[i][jj] + bp[c];
                if (which == 0) {
                    ws[OFF_Q + m * 256 + c] = v;
                } else if (which == 1) {
                    ws[OFF_K + m * 256 + c] = v;
                    ws[OFF_KT + (m >> 7) * 32768 + c * 128 + (m & 127)] = v;
                } else {
                    ws[OFF_V + m * 256 + c] = v;
                }
            }
    } else if (bid < 104) {
        // scalar projections for 32 tokens: wave w handles 8 tokens
        int tk0 = (bid - 96) * 32;
        float* ww = smem;
        ww[t] = Wlr[t]; ww[256 + t] = Wm[t]; ww[512 + t] = Wd[t];
        __syncthreads();
        int wv = t >> 6, lane = t & 63;
        float4 wl = *(const float4*)(ww + lane * 4);
        float4 wmv = *(const float4*)(ww + 256 + lane * 4);
        float4 wdv = *(const float4*)(ww + 512 + lane * 4);
        for (int i = 0; i < 8; ++i) {
            int tok = tk0 + wv * 8 + i;
            float4 xv = *(const float4*)(x + tok * 256 + lane * 4);
            float d0 = dot4(xv, wl), d1 = dot4(xv, wmv), d2 = dot4(xv, wdv);
#pragma unroll
            for (int off = 32; off > 0; off >>= 1) {
                d0 += __shfl_down(d0, off);
                d1 += __shfl_down(d1, off);
                d2 += __shfl_down(d2, off);
            }
            if (lane == 0) {
                ws[OFF_FC + tok] = d0;
                ws[OFF_FC + 256 + tok] = d1;
                ws[OFF_FC + 512 + tok] = d2;
            }
        }
    } else {
        // transpose W1/W2/mW1/mW2 32x32 tiles into CAT slots (512 jobs)
        for (int j2 = bid - 104; j2 < 512; j2 += 152) {
            __syncthreads();
            int mat = j2 >> 7, rem = j2 & 127, b = rem >> 6, tile = rem & 63;
            int r0 = (tile >> 3) * 32, c0 = (tile & 7) * 32;
            const float* src; float* dst;
            if (mat == 0)      { src = W1  + b * 65536; dst = ws + OFF_B1CAT + b * 163840 + 128 * 256; }
            else if (mat == 1) { src = W2  + b * 65536; dst = ws + OFF_B2CAT + b * 163840 + 128 * 256; }
            else if (mat == 2) { src = mW1 + b * 65536; dst = ws + OFF_B1CAT + b * 163840 + 384 * 256; }
            else               { src = mW2 + b * 65536; dst = ws + OFF_B2CAT + b * 163840 + 384 * 256; }
            float (*tl)[33] = (float(*)[33])smem;
            int ttx = t & 31, tty = t >> 5;
#pragma unroll
            for (int i = 0; i < 32; i += 8)
                tl[tty + i][ttx] = src[(r0 + tty + i) * 256 + (c0 + ttx)];
            __syncthreads();
#pragma unroll
            for (int i = 0; i < 32; i += 8)
                dst[(c0 + tty + i) * 256 + (r0 + ttx)] = tl[ttx][tty + i];
        }
    }
    grid_barrier(bar, bid, 1u);

    // ======== S1: z1 GEMM -> X2/X2T/SILD; block 32 does the scans ========
    if (bid < 32) {
        int b = bid >> 4, tile = bid & 15, rowT = tile >> 2, colT = tile & 3;
        float4 c0, c1;
        gemm_tile(ws + OFF_K + b * 32768 + rowT * 32 * 256, 256,
                  ws + OFF_B1CAT + b * 163840 + 128 * 256 + colT * 64, 256, 256,
                  smem, c0, c1);
        float cc[2][4] = {{c0.x, c0.y, c0.z, c0.w}, {c1.x, c1.y, c1.z, c1.w}};
#pragma unroll
        for (int i = 0; i < 2; ++i)
#pragma unroll
            for (int jj = 0; jj < 4; ++jj) {
                int ml = rowT * 32 + 2 * ty + i;
                int n = colT * 64 + 4 * tx + jj;
                float z = cc[i][jj] + b1[b * 256 + n];
                float sg = 1.0f / (1.0f + expf(-z));
                float x2 = z * sg;
                int gm = b * 128 + ml;
                ws[OFF_X2 + gm * 256 + n] = x2;
                ws[OFF_X2T + b * 32768 + n * 128 + ml] = x2;
                ws[OFF_SILD + gm * 256 + n] = x2 + sg * (1.0f - x2);
            }
    } else if (bid == 32) {
        // both batches' scans (t = b*128 + i)
        int i = t & 127;
        float* sm = smem; float* sd = smem + 256; float* se = smem + 512;
        ws[OFF_LR + t] = softplus_f(ws[OFF_FC + t] + blr[0] + LR_SHIFT);
        float lm = -softplus_f(-(ws[OFF_FC + 256 + t] + bm[0]));
        float ld = -softplus_f(ws[OFF_FC + 512 + t] + bd[0]);
        sm[t] = lm; sd[t] = ld;
        __syncthreads();
        for (int off = 1; off < 128; off <<= 1) {
            float am_ = (i >= off) ? sm[t - off] : 0.0f;
            float ad_ = (i >= off) ? sd[t - off] : 0.0f;
            __syncthreads();
            sm[t] += am_; sd[t] += ad_;
            __syncthreads();
        }
        float pm = sm[t], pd = sd[t];
        ws[OFF_PM + t] = pm;
        ws[OFF_PD + t] = pd;
        ws[OFF_MOMCUM + t] = expf(pm);
        ws[OFF_WDCUM + t] = expf(pd);
        se[t] = expf(pm - pd);
        __syncthreads();
        for (int off = 1; off < 128; off <<= 1) {
            float a_ = (i >= off) ? se[t - off] : 0.0f;
            __syncthreads();
            se[t] += a_;
            __syncthreads();
        }
        ws[OFF_C + t] = expf(pd) * se[t];
    }
    grid_barrier(bar, bid, 2u);

    // ======== S2: z2 GEMM (blocks 0-31); decay A + A1CAT q-slots (32-255) ====
    if (bid < 32) {
        int b = bid >> 4, tile = bid & 15, rowT = tile >> 2, colT = tile & 3;
        float4 c0, c1;
        gemm_tile(ws + OFF_X2 + b * 32768 + rowT * 32 * 256, 256,
                  ws + OFF_B2CAT + b * 163840 + 128 * 256 + colT * 64, 256, 256,
                  smem, c0, c1);
        float cc[2][4] = {{c0.x, c0.y, c0.z, c0.w}, {c1.x, c1.y, c1.z, c1.w}};
#pragma unroll
        for (int i = 0; i < 2; ++i)
#pragma unroll
            for (int jj = 0; jj < 4; ++jj) {
                int ml = rowT * 32 + 2 * ty + i;
                int n = colT * 64 + 4 * tx + jj;
                int gm = b * 128 + ml;
                float gz2 = cc[i][jj] + b2[b * 256 + n] - ws[OFF_V + gm * 256 + n];
                ws[OFF_B2CAT + b * 163840 + ml * 256 + n] = gz2;
            }
    } else {
        for (int bl = bid - 32; bl < 256; bl += 224) {
            __syncthreads();
            int b = bl >> 7, l = bl & 127;
            if (t < 128) {
                float a = 0.0f;
                if (t <= l) {
                    const float* Pm = ws + OFF_PM + b * 128;
                    const float* Pd = ws + OFF_PD + b * 128;
                    float pdl = Pd[l], pmm = Pm[t], s = 0.0f;
                    for (int mm = t; mm <= l; ++mm)
                        s += expf((pdl - Pd[mm]) + (Pm[mm] - pmm));
                    a = s;
                }
                ws[OFF_A + bl * 128 + t] = a;
            }
            float q  = ws[OFF_Q + bl * 256 + t];
            float wdv = ws[OFF_WDCUM + b * 128 + l];
            float cl = ws[OFF_C + b * 128 + l];
            float* A1 = ws + OFF_A1CAT + b * 81920 + l * 640;
            A1[128 + t] = wdv * q;
            A1[384 + t] = -cl * q;
        }
    }
    grid_barrier(bar, bid, 3u);

    // ======== S3: gx2 GEMM -> GZ1; lastw fam=1 (W2p/mgW2) ========
    if (bid < 32) {
        int b = bid >> 4, tile = bid & 15, rowT = tile >> 2, colT = tile & 3;
        float4 c0, c1;
        gemm_tile(ws + OFF_B2CAT + b * 163840 + rowT * 32 * 256, 256,
                  W2 + b * 65536 + colT * 64, 256, 256, smem, c0, c1);
        float cc[2][4] = {{c0.x, c0.y, c0.z, c0.w}, {c1.x, c1.y, c1.z, c1.w}};
#pragma unroll
        for (int i = 0; i < 2; ++i)
#pragma unroll
            for (int jj = 0; jj < 4; ++jj) {
                int ml = rowT * 32 + 2 * ty + i;
                int n = colT * 64 + 4 * tx + jj;
                int gm = b * 128 + ml;
                float gz1 = cc[i][jj] * ws[OFF_SILD + gm * 256 + n];
                ws[OFF_B1CAT + b * 163840 + ml * 256 + n] = gz1;
            }
    } else if (bid < 160) {
        int jdx = bid - 32, b = jdx >> 6, tile = jdx & 63;
        lastw_job(b, 1, (tile >> 3) * 32, (tile & 7) * 32,
                  W1, mW1, W2, mW2, ws, out, smem);
    }
    grid_barrier(bar, bid, 4u);

    // ======== S4: zq1 (score1 inline, K=640); lastw fam=0; lastb ========
    if (bid < 32) {
        int b = bid >> 4, tile = bid & 15, rowT = tile >> 2, colT = tile & 3;
        // score part: this block computes P1 rows [rowT*32,+32), cols 0..127
        // (the 4 colT blocks per rowT produce bit-identical copies; benign)
        for (int c2 = 0; c2 < 2; ++c2) {
            __syncthreads();
            if (c2 * 64 > rowT * 32 + 31) {
                for (int e = t; e < 2048; e += 256) {
                    int l = rowT * 32 + (e >> 6), mc = c2 * 64 + (e & 63);
                    ws[OFF_A1CAT + b * 81920 + l * 640 + mc] = 0.0f;
                }
            } else {
                float4 c0, c1;
                gemm_tile(ws + OFF_Q + b * 32768 + rowT * 32 * 256, 256,
                          ws + OFF_KT + b * 32768 + c2 * 64, 128, 256, smem, c0, c1);
                float cc[2][4] = {{c0.x, c0.y, c0.z, c0.w}, {c1.x, c1.y, c1.z, c1.w}};
#pragma unroll
                for (int i = 0; i < 2; ++i)
#pragma unroll
                    for (int jj = 0; jj < 4; ++jj) {
                        int l = rowT * 32 + 2 * ty + i;
                        int mc = c2 * 64 + 4 * tx + jj;
                        float p = 0.0f;
                        if (mc <= l)
                            p = ws[OFF_A + (b * 128 + l) * 128 + mc] *
                                ws[OFF_LR + b * 128 + mc] * (1.0f + cc[i][jj]);
                        ws[OFF_A1CAT + b * 81920 + l * 640 + mc] = p;
                    }
            }
        }
        __syncthreads();
        float4 c0, c1;
        gemm_tile(ws + OFF_A1CAT + b * 81920 + rowT * 32 * 640, 640,
                  ws + OFF_B1CAT + b * 163840 + colT * 64, 256, 640, smem, c0, c1);
        float cc[2][4] = {{c0.x, c0.y, c0.z, c0.w}, {c1.x, c1.y, c1.z, c1.w}};
#pragma unroll
        for (int i = 0; i < 2; ++i)
#pragma unroll
            for (int jj = 0; jj < 4; ++jj) {
                int ml = rowT * 32 + 2 * ty + i;
                int n = colT * 64 + 4 * tx + jj;
                float cl = ws[OFF_C + b * 128 + ml];
                float wdv = ws[OFF_WDCUM + b * 128 + ml];
                float z = cc[i][jj] + wdv * b1[b * 256 + n] - cl * mb1[b * 256 + n];
                float sg = 1.0f / (1.0f + expf(-z));
                float xq = z * sg;
                ws[OFF_XQ + (b * 128 + ml) * 256 + n] = xq;
                float* A2 = ws + OFF_A2CAT + b * 81920 + ml * 640;
                A2[128 + n] = wdv * xq;
                A2[384 + n] = -cl * xq;
            }
    } else if (bid < 160) {
        int jdx = bid - 32, b = jdx >> 6, tile = jdx & 63;
        lastw_job(b, 0, (tile >> 3) * 32, (tile & 7) * 32,
                  W1, mW1, W2, mW2, ws, out, smem);
    } else if (bid < 162) {
        int b = bid - 160;
        float* wa = smem; float* wm = smem + 128;
        if (t < 128) {
            float lrv = ws[OFF_LR + b * 128 + t];
            wa[t] = ws[OFF_A + (b * 128 + 127) * 128 + t] * lrv;
            wm[t] = expf(ws[OFF_PM + b * 128 + 127] - ws[OFF_PM + b * 128 + t]) * lrv;
        }
        __syncthreads();
        const float* gz1 = ws + OFF_B1CAT + b * 163840;
        const float* gz2 = ws + OFF_B2CAT + b * 163840;
        float sA1 = 0, sM1 = 0, sA2 = 0, sM2 = 0;
#pragma unroll 4
        for (int m = 0; m < 128; ++m) {
            float g1 = gz1[m * 256 + t], g2 = gz2[m * 256 + t];
            sA1 += wa[m] * g1; sM1 += wm[m] * g1;
            sA2 += wa[m] * g2; sM2 += wm[m] * g2;
        }
        float c_last  = ws[OFF_C + b * 128 + 127];
        float wd_last = ws[OFF_WDCUM + b * 128 + 127];
        float mc_last = ws[OFF_MOMCUM + b * 128 + 127];
        out[OUT_B1P + b * 256 + t]  = sA1 - c_last * mb1[b * 256 + t] + wd_last * b1[b * 256 + t];
        out[OUT_MGB1 + b * 256 + t] = sM1 - mc_last * mb1[b * 256 + t];
        out[OUT_B2P + b * 256 + t]  = sA2 - c_last * mb2[b * 256 + t] + wd_last * b2[b * 256 + t];
        out[OUT_MGB2 + b * 256 + t] = sM2 - mc_last * mb2[b * 256 + t];
    }
    grid_barrier(bar, bid, 5u);

    // ======== S5: zq2 (score2 inline, K=640) -> out ========
    if (bid < 32) {
        int b = bid >> 4, tile = bid & 15, rowT = tile >> 2, colT = tile & 3;
        for (int c2 = 0; c2 < 2; ++c2) {
            __syncthreads();
            if (c2 * 64 > rowT * 32 + 31) {
                for (int e = t; e < 2048; e += 256) {
                    int l = rowT * 32 + (e >> 6), mc = c2 * 64 + (e & 63);
                    ws[OFF_A2CAT + b * 81920 + l * 640 + mc] = 0.0f;
                }
            } else {
                float4 c0, c1;
                gemm_tile(ws + OFF_XQ + b * 32768 + rowT * 32 * 256, 256,
                          ws + OFF_X2T + b * 32768 + c2 * 64, 128, 256, smem, c0, c1);
                float cc[2][4] = {{c0.x, c0.y, c0.z, c0.w}, {c1.x, c1.y, c1.z, c1.w}};
#pragma unroll
                for (int i = 0; i < 2; ++i)
#pragma unroll
                    for (int jj = 0; jj < 4; ++jj) {
                        int l = rowT * 32 + 2 * ty + i;
                        int mc = c2 * 64 + 4 * tx + jj;
                        float p = 0.0f;
                        if (mc <= l)
                            p = ws[OFF_A + (b * 128 + l) * 128 + mc] *
                                ws[OFF_LR + b * 128 + mc] * (1.0f + cc[i][jj]);
                        ws[OFF_A2CAT + b * 81920 + l * 640 + mc] = p;
                    }
            }
        }
        __syncthreads();
        float4 c0, c1;
        gemm_tile(ws + OFF_A2CAT + b * 81920 + rowT * 32 * 640, 640,
                  ws + OFF_B2CAT + b * 163840 + colT * 64, 256, 640, smem, c0, c1);
        float cc[2][4] = {{c0.x, c0.y, c0.z, c0.w}, {c1.x, c1.y, c1.z, c1.w}};
#pragma unroll
        for (int i = 0; i < 2; ++i)
#pragma unroll
            for (int jj = 0; jj < 4; ++jj) {
                int ml = rowT * 32 + 2 * ty + i;
                int n = colT * 64 + 4 * tx + jj;
                float cl = ws[OFF_C + b * 128 + ml];
                float wdv = ws[OFF_WDCUM + b * 128 + ml];
                out[OUT_ZQ2 + (b * 128 + ml) * 256 + n] =
                    cc[i][jj] + wdv * b2[b * 256 + n] - cl * mb2[b * 256 + n];
            }
    }
}

// ---------------------------------------------------------------------------
extern "C" void kernel_launch(void* const* d_in, const int* in_sizes, int n_in,
                              void* d_out, int out_size, void* d_ws, size_t ws_size,
                              hipStream_t stream) {
    const float* x   = (const float*)d_in[0];
    const float* Wq  = (const float*)d_in[1];
    const float* bq  = (const float*)d_in[2];
    const float* Wk  = (const float*)d_in[3];
    const float* bk  = (const float*)d_in[4];
    const float* Wv  = (const float*)d_in[5];
    const float* bv  = (const float*)d_in[6];
    const float* Wlr = (const float*)d_in[7];
    const float* blr = (const float*)d_in[8];
    const float* Wm  = (const float*)d_in[9];
    const float* bm  = (const float*)d_in[10];
    const float* Wd  = (const float*)d_in[11];
    const float* bd  = (const float*)d_in[12];
    const float* W1  = (const float*)d_in[13];
    const float* b1  = (const float*)d_in[14];
    const float* W2  = (const float*)d_in[15];
    const float* b2  = (const float*)d_in[16];
    const float* mW1 = (const float*)d_in[17];
    const float* mb1 = (const float*)d_in[18];
    const float* mW2 = (const float*)d_in[19];
    const float* mb2 = (const float*)d_in[20];
    float* ws  = (float*)d_ws;
    float* out = (float*)d_out;

    fused_kernel<<<NBLK, 256, 0, stream>>>(
        x, Wq, bq, Wk, bk, Wv, bv, Wlr, blr, Wm, bm, Wd, bd,
        W1, b1, W2, b2, mW1, mb1, mW2, mb2, ws, out);
}